// Round 8
// baseline (236.828 us; speedup 1.0000x reference)
//
#include <hip/hip_runtime.h>
#include <hip/hip_bf16.h>

#define C 32
#define R 8
#define SCAN_G 16384   // 64 blocks x 256 threads
#define NPB 32         // nodes per block in k_nodeZ

typedef unsigned int u32;
__device__ __forceinline__ float bflo(u32 u) { return __uint_as_float(u << 16); }
__device__ __forceinline__ float bfhi(u32 u) { return __uint_as_float(u & 0xffff0000u); }
// f32 -> bf16 bits with round-to-nearest-even
__device__ __forceinline__ u32 f2bf_bits(float f) {
    u32 u = __float_as_uint(f);
    u32 lsb = (u >> 16) & 1u;
    return (u + 0x7fffu + lsb) >> 16;
}

// ---- M[r][c][j] = sum_o W_tp[c][r][o] * W1[r*C+o][j]   (f32, 32 KB) ----
__global__ void k_prepM(const float* __restrict__ Wtp, const float* __restrict__ W1,
                        float* __restrict__ M) {
    int idx = blockIdx.x * 256 + threadIdx.x;
    if (idx >= R * C * C) return;
    int r = idx >> 10;
    int c = (idx >> 5) & 31;
    int j = idx & 31;
    float acc = 0.f;
#pragma unroll
    for (int o = 0; o < C; ++o)
        acc = fmaf(Wtp[c * R * C + r * C + o], W1[(r * C + o) * C + j], acc);
    M[idx] = acc;
}

// ---- z[n][j][r] = sum_c x[n][c] * M[r][c][j]  (bf16; r contiguous), x via LDS ----
__global__ void k_nodeZ(const float* __restrict__ x, const float* __restrict__ M,
                        __hip_bfloat16* __restrict__ z, int N) {
    __shared__ float xs[NPB * C];
    int t = threadIdx.x;
    int n0 = blockIdx.x * NPB;
    for (int i = t * 4; i < NPB * C; i += 256 * 4) {
        size_t gbase = (size_t)n0 * C + i;
        float4 v = make_float4(0.f, 0.f, 0.f, 0.f);
        if (gbase + 3 < (size_t)N * C) v = *(const float4*)(x + gbase);
        *(float4*)(xs + i) = v;
    }
    __syncthreads();
    int r = t & 7, j = t >> 3;
    float m[C];
#pragma unroll
    for (int c = 0; c < C; ++c) m[c] = M[r * C * C + c * C + j];
    int nmax = N - n0; if (nmax > NPB) nmax = NPB;
    for (int nn = 0; nn < nmax; ++nn) {
        const float* xp = xs + nn * C;
        float acc = 0.f;
#pragma unroll
        for (int c = 0; c < C; ++c) acc = fmaf(xp[c], m[c], acc);
        z[(size_t)(n0 + nn) * (R * C) + t] = __float2bfloat16(acc);
    }
}

// ---- CSR build ----
__global__ void k_hist(const int* __restrict__ ei, int* __restrict__ hist, int E, int N) {
    int i = blockIdx.x * blockDim.x + threadIdx.x;
    int stride = gridDim.x * blockDim.x;
    for (; i < E; i += stride) {
        int r = ei[i];
        r = ((unsigned)r < (unsigned)N) ? r : 0;
        atomicAdd(&hist[r], 1);
    }
}

__global__ void k_scan1(const int* __restrict__ hist, int* __restrict__ tsum,
                        int N, int CH) {
    int t = blockIdx.x * blockDim.x + threadIdx.x;
    int a0 = t * CH;
    int a1 = a0 + CH; if (a1 > N) a1 = N;
    int s = 0;
    for (int a = a0; a < a1; ++a) s += hist[a];
    tsum[t] = s;
}

__global__ void k_scan2(int* __restrict__ tsum) {
    __shared__ int s[1024];
    int t = threadIdx.x;
    int vals[16];
    int sum = 0;
#pragma unroll
    for (int i = 0; i < 16; ++i) { vals[i] = tsum[t * 16 + i]; sum += vals[i]; }
    s[t] = sum;
    __syncthreads();
    for (int off = 1; off < 1024; off <<= 1) {
        int v = (t >= off) ? s[t - off] : 0;
        __syncthreads();
        s[t] += v;
        __syncthreads();
    }
    int base = (t == 0) ? 0 : s[t - 1];
#pragma unroll
    for (int i = 0; i < 16; ++i) { tsum[t * 16 + i] = base; base += vals[i]; }
}

__global__ void k_scan3(const int* __restrict__ hist, const int* __restrict__ tsum,
                        int* __restrict__ rowptr, int* __restrict__ cursor,
                        int N, int CH, int E) {
    int t = blockIdx.x * blockDim.x + threadIdx.x;
    int a0 = t * CH;
    int a1 = a0 + CH; if (a1 > N) a1 = N;
    int run = tsum[t];
    for (int a = a0; a < a1; ++a) {
        rowptr[a] = run;
        cursor[a] = run;
        run += hist[a];
    }
    if (t == 0) rowptr[N] = E;
}

// ---- step 1: tiny scattered write — eid[p] = edge index (4B) ----
__global__ void k_scatter_idx(const int* __restrict__ ei, int* __restrict__ cursor,
                              int* __restrict__ eid, int E, int N) {
    int i = blockIdx.x * blockDim.x + threadIdx.x;
    int stride = gridDim.x * blockDim.x;
    for (; i < E; i += stride) {
        int r = ei[i];
        r = ((unsigned)r < (unsigned)N) ? r : 0;
        int p = atomicAdd(&cursor[r], 1);
        eid[p] = i;
    }
}

// ---- step 2: coalesced record build: recs[p] = {col, pad, rbf01..67} ----
__global__ void k_build_recs(const int* __restrict__ eid, const int* __restrict__ ei,
                             const float* __restrict__ pos, uint4* __restrict__ recs,
                             int E, int N) {
    int p = blockIdx.x * blockDim.x + threadIdx.x;
    int stride = gridDim.x * blockDim.x;
    for (; p < E; p += stride) {
        int i = eid[p];
        int r = ei[i];
        int c = ei[E + i];
        r = ((unsigned)r < (unsigned)N) ? r : 0;
        c = ((unsigned)c < (unsigned)N) ? c : 0;
        float dx = pos[r * 3 + 0] - pos[c * 3 + 0];
        float dy = pos[r * 3 + 1] - pos[c * 3 + 1];
        float dz = pos[r * 3 + 2] - pos[c * 3 + 2];
        float dist = sqrtf(fmaf(dx, dx, fmaf(dy, dy, dz * dz)) + 1e-12f);
        // centers = linspace(0,5,8), width = 5/7, scaling = 1/sqrt(2pi)
        u32 rb[R];
#pragma unroll
        for (int rr = 0; rr < R; ++rr) {
            float t = (dist - 0.71428573f * (float)rr) * 1.3999999f;
            rb[rr] = f2bf_bits(0.3989423f * __expf(-0.5f * t * t));
        }
        uint4 w0, w1;
        w0.x = (u32)c;
        w0.y = 0u;
        w0.z = rb[0] | (rb[1] << 16);
        w0.w = rb[2] | (rb[3] << 16);
        w1.x = rb[4] | (rb[5] << 16);
        w1.y = rb[6] | (rb[7] << 16);
        w1.z = 0u; w1.w = 0u;
        recs[2 * p + 0] = w0;
        recs[2 * p + 1] = w1;
    }
}

// h = b1 + sum_r rbf[r] * z[col][j][r]
__device__ __forceinline__ float edge_dot(uint4 r0, uint4 r1, uint4 zv, float b1j) {
    float h = b1j;
    h = fmaf(bflo(r0.z), bflo(zv.x), h);
    h = fmaf(bfhi(r0.z), bfhi(zv.x), h);
    h = fmaf(bflo(r0.w), bflo(zv.y), h);
    h = fmaf(bfhi(r0.w), bfhi(zv.y), h);
    h = fmaf(bflo(r1.x), bflo(zv.z), h);
    h = fmaf(bfhi(r1.x), bfhi(zv.z), h);
    h = fmaf(bflo(r1.y), bflo(zv.w), h);
    h = fmaf(bfhi(r1.y), bfhi(zv.w), h);
    return h;
}
__device__ __forceinline__ float silu_f(float h) {
    return h * __builtin_amdgcn_rcpf(1.f + __expf(-h));
}

// ---- per-row edge kernel: 32 lanes = one row; records pre-baked; fused epilogue ----
__global__ void k_edge_csr(const int* __restrict__ rowptr, const uint4* __restrict__ recs,
                           const __hip_bfloat16* __restrict__ z,
                           const float* __restrict__ x, const float* __restrict__ b1,
                           const float* __restrict__ W2, const float* __restrict__ b2,
                           float* __restrict__ out, int N) {
    __shared__ float W2s[C * C];
    for (int i = threadIdx.x; i < C * C; i += blockDim.x) W2s[i] = W2[i];
    __syncthreads();
    int gt = blockIdx.x * blockDim.x + threadIdx.x;
    int j = gt & 31;
    int n = gt >> 5;
    if (n >= N) return;
    int p0 = rowptr[n];
    int p1 = rowptr[n + 1];
    float b1j = b1[j];
    float acc = 0.f;
    int p = p0;
    for (; p + 4 <= p1; p += 4) {
        uint4 a0 = recs[2 * p + 0], a1 = recs[2 * p + 1];
        uint4 b0 = recs[2 * p + 2], b1r = recs[2 * p + 3];
        uint4 c0 = recs[2 * p + 4], c1 = recs[2 * p + 5];
        uint4 d0 = recs[2 * p + 6], d1 = recs[2 * p + 7];
        uint4 za = ((const uint4*)(z + (size_t)a0.x * (R * C)))[j];
        uint4 zb = ((const uint4*)(z + (size_t)b0.x * (R * C)))[j];
        uint4 zc = ((const uint4*)(z + (size_t)c0.x * (R * C)))[j];
        uint4 zd = ((const uint4*)(z + (size_t)d0.x * (R * C)))[j];
        float ha = edge_dot(a0, a1, za, b1j);
        float hb = edge_dot(b0, b1r, zb, b1j);
        float hc = edge_dot(c0, c1, zc, b1j);
        float hd = edge_dot(d0, d1, zd, b1j);
        acc += silu_f(ha) + silu_f(hb) + silu_f(hc) + silu_f(hd);
    }
    for (; p < p1; ++p) {
        uint4 a0 = recs[2 * p + 0], a1 = recs[2 * p + 1];
        uint4 za = ((const uint4*)(z + (size_t)a0.x * (R * C)))[j];
        acc += silu_f(edge_dot(a0, a1, za, b1j));
    }
    // epilogue: out[n][j] = x[n][j] + sum_i acc_i * W2[i][j] + deg * b2[j]
    float v = fmaf((float)(p1 - p0), b2[j], x[(size_t)n * C + j]);
#pragma unroll
    for (int i = 0; i < C; ++i)
        v = fmaf(__shfl(acc, i, 32), W2s[i * C + j], v);
    out[(size_t)n * C + j] = v;
}

// rbf for fallback tiers
__device__ __forceinline__ float rbf_lane(float dist, int r) {
    float t = (dist - 0.71428573f * (float)r) * 1.3999999f;
    return 0.3989423f * __expf(-0.5f * t * t);
}

// ---- Tier B kernels (proven fallback) ----
__global__ void k_edge_direct(const int* __restrict__ ei, const float* __restrict__ pos,
                              const float* __restrict__ x, const float* __restrict__ M,
                              const float* __restrict__ b1,
                              float* __restrict__ agg, float* __restrict__ deg,
                              int E, int N) {
    __shared__ float Ms[R * C * C];
    for (int i = threadIdx.x; i < R * C * C; i += blockDim.x) Ms[i] = M[i];
    __syncthreads();
    int gt = blockIdx.x * blockDim.x + threadIdx.x;
    int j = gt & 31;
    int g = gt >> 5;
    int ngroups = (gridDim.x * blockDim.x) >> 5;
    float b1j = b1[j];
    for (int e = g; e < E; e += ngroups) {
        int row = ei[e];
        int col = ei[E + e];
        row = ((unsigned)row < (unsigned)N) ? row : 0;
        col = ((unsigned)col < (unsigned)N) ? col : 0;
        float dx = pos[row * 3 + 0] - pos[col * 3 + 0];
        float dy = pos[row * 3 + 1] - pos[col * 3 + 1];
        float dz = pos[row * 3 + 2] - pos[col * 3 + 2];
        float dist = sqrtf(fmaf(dx, dx, fmaf(dy, dy, dz * dz)) + 1e-12f);
        float my_rbf = rbf_lane(dist, j & 7);
        float xr[C];
#pragma unroll
        for (int c = 0; c < C; ++c) xr[c] = x[(size_t)col * C + c];
        float h = b1j;
#pragma unroll
        for (int r = 0; r < R; ++r) {
            float s = 0.f;
#pragma unroll
            for (int c = 0; c < C; ++c)
                s = fmaf(xr[c], Ms[r * C * C + c * C + j], s);
            h = fmaf(__shfl(my_rbf, r, 32), s, h);
        }
        float sh = h / (1.f + __expf(-h));
        atomicAdd(&agg[(size_t)row * C + j], sh);
        if (j == 0) atomicAdd(&deg[row], 1.f);
    }
}

__global__ void k_final(const float* __restrict__ x, const float* __restrict__ agg,
                        const float* __restrict__ deg, const float* __restrict__ W2,
                        const float* __restrict__ b2, float* __restrict__ out,
                        int N) {
    int t = threadIdx.x;
    int j = t & 31;
    float w2[C];
#pragma unroll
    for (int i = 0; i < C; ++i) w2[i] = W2[i * C + j];
    float b2j = b2[j];
    int g = (blockIdx.x * blockDim.x + t) >> 5;
    int ngroups = (gridDim.x * blockDim.x) >> 5;
    for (int n = g; n < N; n += ngroups) {
        const float* ap = agg + (size_t)n * C;
        float acc = 0.f;
#pragma unroll
        for (int i = 0; i < C; ++i) acc = fmaf(ap[i], w2[i], acc);
        out[(size_t)n * C + j] = x[(size_t)n * C + j] + acc + deg[n] * b2j;
    }
}

// ---- Tier C (no usable ws) ----
__global__ void k_edge_full(const int* __restrict__ ei, const float* __restrict__ pos,
                            const float* __restrict__ x,
                            const float* __restrict__ Wtp, const float* __restrict__ W1,
                            const float* __restrict__ b1,
                            const float* __restrict__ W2, const float* __restrict__ b2,
                            float* __restrict__ out, int E, int N) {
    __shared__ float Ms[R * C * C];
    __shared__ float W2s[C * C];
    for (int idx = threadIdx.x; idx < R * C * C; idx += blockDim.x) {
        int r = idx >> 10, c = (idx >> 5) & 31, jj = idx & 31;
        float acc = 0.f;
#pragma unroll
        for (int o = 0; o < C; ++o)
            acc = fmaf(Wtp[c * R * C + r * C + o], W1[(r * C + o) * C + jj], acc);
        Ms[idx] = acc;
    }
    for (int idx = threadIdx.x; idx < C * C; idx += blockDim.x) W2s[idx] = W2[idx];
    __syncthreads();
    int gt = blockIdx.x * blockDim.x + threadIdx.x;
    int j = gt & 31;
    int g = gt >> 5;
    int ngroups = (gridDim.x * blockDim.x) >> 5;
    float b1j = b1[j];
    float b2j = b2[j];
    for (int e = g; e < E; e += ngroups) {
        int row = ei[e];
        int col = ei[E + e];
        row = ((unsigned)row < (unsigned)N) ? row : 0;
        col = ((unsigned)col < (unsigned)N) ? col : 0;
        float dx = pos[row * 3 + 0] - pos[col * 3 + 0];
        float dy = pos[row * 3 + 1] - pos[col * 3 + 1];
        float dz = pos[row * 3 + 2] - pos[col * 3 + 2];
        float dist = sqrtf(fmaf(dx, dx, fmaf(dy, dy, dz * dz)) + 1e-12f);
        float my_rbf = rbf_lane(dist, j & 7);
        float xr[C];
#pragma unroll
        for (int c = 0; c < C; ++c) xr[c] = x[(size_t)col * C + c];
        float h = b1j;
#pragma unroll
        for (int r = 0; r < R; ++r) {
            float s = 0.f;
#pragma unroll
            for (int c = 0; c < C; ++c)
                s = fmaf(xr[c], Ms[r * C * C + c * C + j], s);
            h = fmaf(__shfl(my_rbf, r, 32), s, h);
        }
        float sh = h / (1.f + __expf(-h));
        float v = b2j;
#pragma unroll
        for (int i = 0; i < C; ++i)
            v = fmaf(__shfl(sh, i, 32), W2s[i * C + j], v);
        atomicAdd(&out[(size_t)row * C + j], v);
    }
}

__global__ void k_add_x(const float* __restrict__ x, float* __restrict__ out, int total) {
    int i = blockIdx.x * blockDim.x + threadIdx.x;
    int stride = gridDim.x * blockDim.x;
    for (; i < total; i += stride) out[i] += x[i];
}

extern "C" void kernel_launch(void* const* d_in, const int* in_sizes, int n_in,
                              void* d_out, int out_size, void* d_ws, size_t ws_size,
                              hipStream_t stream) {
    const float* x   = (const float*)d_in[0];
    const float* pos = (const float*)d_in[1];
    const int*   ei  = (const int*)d_in[2];
    const float* Wtp = (const float*)d_in[3];
    const float* W1  = (const float*)d_in[4];
    const float* b1  = (const float*)d_in[5];
    const float* W2  = (const float*)d_in[6];
    const float* b2  = (const float*)d_in[7];
    int N = in_sizes[0] / C;
    int E = in_sizes[2] / 2;

    char* ws = (char*)d_ws;
    size_t mBytes   = (size_t)R * C * C * sizeof(float);              // 32 KB
    size_t zBytes   = (size_t)N * R * C * sizeof(__hip_bfloat16);     // 25.6 MB
    size_t histB    = (size_t)N * sizeof(int);
    size_t rowptrB  = (size_t)(N + 1) * sizeof(int);
    size_t cursorB  = (size_t)N * sizeof(int);
    size_t eidB     = (size_t)E * sizeof(int);                        // 3.2 MB
    size_t recsB    = (size_t)E * 32;                                 // 25.6 MB
    size_t tsumB    = (size_t)SCAN_G * sizeof(int);                   // 64 KB
    size_t aggBytes = (size_t)N * (C + 1) * sizeof(float);            // tier B
    size_t tierANeed = mBytes + zBytes + histB + rowptrB + cursorB + eidB + recsB + tsumB;
    bool tierA = ws_size >= tierANeed;
    bool tierB = !tierA && ws_size >= mBytes + aggBytes;

    if (tierA) {
        size_t off = 0;
        float*          M      = (float*)(ws + off); off += mBytes;
        __hip_bfloat16* z      = (__hip_bfloat16*)(ws + off); off += zBytes;
        int*            hist   = (int*)(ws + off); off += histB;
        int*            rowptr = (int*)(ws + off); off += rowptrB;
        int*            cursor = (int*)(ws + off); off += cursorB;
        int*            eid    = (int*)(ws + off); off += eidB;
        uint4*          recs   = (uint4*)(ws + off); off += recsB;
        int*            tsum   = (int*)(ws + off);

        int CH = (N + SCAN_G - 1) / SCAN_G;
        hipMemsetAsync(hist, 0, histB, stream);
        k_prepM<<<(R * C * C + 255) / 256, 256, 0, stream>>>(Wtp, W1, M);
        k_nodeZ<<<(N + NPB - 1) / NPB, 256, 0, stream>>>(x, M, z, N);
        k_hist<<<(E + 255) / 256, 256, 0, stream>>>(ei, hist, E, N);
        k_scan1<<<SCAN_G / 256, 256, 0, stream>>>(hist, tsum, N, CH);
        k_scan2<<<1, 1024, 0, stream>>>(tsum);
        k_scan3<<<SCAN_G / 256, 256, 0, stream>>>(hist, tsum, rowptr, cursor, N, CH, E);
        k_scatter_idx<<<(E + 255) / 256, 256, 0, stream>>>(ei, cursor, eid, E, N);
        k_build_recs<<<(E + 255) / 256, 256, 0, stream>>>(eid, ei, pos, recs, E, N);
        int blocks = (int)(((size_t)N * 32 + 255) / 256);
        k_edge_csr<<<blocks, 256, 0, stream>>>(rowptr, recs, z, x, b1, W2, b2,
                                               (float*)d_out, N);
    } else if (tierB) {
        float* M   = (float*)ws;
        float* agg = (float*)(ws + mBytes);
        float* deg = agg + (size_t)N * C;
        hipMemsetAsync(agg, 0, aggBytes, stream);
        k_prepM<<<(R * C * C + 255) / 256, 256, 0, stream>>>(Wtp, W1, M);
        k_edge_direct<<<2048, 256, 0, stream>>>(ei, pos, x, M, b1, agg, deg, E, N);
        k_final<<<1024, 256, 0, stream>>>(x, agg, deg, W2, b2, (float*)d_out, N);
    } else {
        hipMemsetAsync(d_out, 0, (size_t)N * C * sizeof(float), stream);
        k_edge_full<<<1024, 256, 0, stream>>>(ei, pos, x, Wtp, W1, b1, W2, b2,
                                              (float*)d_out, E, N);
        k_add_x<<<1024, 256, 0, stream>>>(x, (float*)d_out, N * C);
    }
}

// Round 9
// 208.649 us; speedup vs baseline: 1.1351x; 1.1351x over previous
//
#include <hip/hip_runtime.h>
#include <hip/hip_bf16.h>

#define C 32
#define R 8
#define SCAN_G 16384   // 64 blocks x 256 threads
#define NPB 32         // nodes per block in k_nodeZ

typedef unsigned int u32;
__device__ __forceinline__ float bflo(u32 u) { return __uint_as_float(u << 16); }
__device__ __forceinline__ float bfhi(u32 u) { return __uint_as_float(u & 0xffff0000u); }
// f32 -> bf16 bits with round-to-nearest-even
__device__ __forceinline__ u32 f2bf_bits(float f) {
    u32 u = __float_as_uint(f);
    u32 lsb = (u >> 16) & 1u;
    return (u + 0x7fffu + lsb) >> 16;
}

// ---- M[r][c][j] = sum_o W_tp[c][r][o] * W1[r*C+o][j]   (f32, 32 KB) ----
__global__ void k_prepM(const float* __restrict__ Wtp, const float* __restrict__ W1,
                        float* __restrict__ M) {
    int idx = blockIdx.x * 256 + threadIdx.x;
    if (idx >= R * C * C) return;
    int r = idx >> 10;
    int c = (idx >> 5) & 31;
    int j = idx & 31;
    float acc = 0.f;
#pragma unroll
    for (int o = 0; o < C; ++o)
        acc = fmaf(Wtp[c * R * C + r * C + o], W1[(r * C + o) * C + j], acc);
    M[idx] = acc;
}

// ---- z[n][j][r] = sum_c x[n][c] * M[r][c][j]  (bf16; r contiguous), x via LDS ----
__global__ void k_nodeZ(const float* __restrict__ x, const float* __restrict__ M,
                        __hip_bfloat16* __restrict__ z, int N) {
    __shared__ float xs[NPB * C];
    int t = threadIdx.x;
    int n0 = blockIdx.x * NPB;
    for (int i = t * 4; i < NPB * C; i += 256 * 4) {
        size_t gbase = (size_t)n0 * C + i;
        float4 v = make_float4(0.f, 0.f, 0.f, 0.f);
        if (gbase + 3 < (size_t)N * C) v = *(const float4*)(x + gbase);
        *(float4*)(xs + i) = v;
    }
    __syncthreads();
    int r = t & 7, j = t >> 3;
    float m[C];
#pragma unroll
    for (int c = 0; c < C; ++c) m[c] = M[r * C * C + c * C + j];
    int nmax = N - n0; if (nmax > NPB) nmax = NPB;
    for (int nn = 0; nn < nmax; ++nn) {
        const float* xp = xs + nn * C;
        float acc = 0.f;
#pragma unroll
        for (int c = 0; c < C; ++c) acc = fmaf(xp[c], m[c], acc);
        z[(size_t)(n0 + nn) * (R * C) + t] = __float2bfloat16(acc);
    }
}

// ---- CSR build ----
__global__ void k_hist(const int* __restrict__ ei, int* __restrict__ hist, int E, int N) {
    int i = blockIdx.x * blockDim.x + threadIdx.x;
    int stride = gridDim.x * blockDim.x;
    for (; i < E; i += stride) {
        int r = ei[i];
        r = ((unsigned)r < (unsigned)N) ? r : 0;
        atomicAdd(&hist[r], 1);
    }
}

__global__ void k_scan1(const int* __restrict__ hist, int* __restrict__ tsum,
                        int N, int CH) {
    int t = blockIdx.x * blockDim.x + threadIdx.x;
    int a0 = t * CH;
    int a1 = a0 + CH; if (a1 > N) a1 = N;
    int s = 0;
    for (int a = a0; a < a1; ++a) s += hist[a];
    tsum[t] = s;
}

__global__ void k_scan2(int* __restrict__ tsum) {
    __shared__ int s[1024];
    int t = threadIdx.x;
    int vals[16];
    int sum = 0;
#pragma unroll
    for (int i = 0; i < 16; ++i) { vals[i] = tsum[t * 16 + i]; sum += vals[i]; }
    s[t] = sum;
    __syncthreads();
    for (int off = 1; off < 1024; off <<= 1) {
        int v = (t >= off) ? s[t - off] : 0;
        __syncthreads();
        s[t] += v;
        __syncthreads();
    }
    int base = (t == 0) ? 0 : s[t - 1];
#pragma unroll
    for (int i = 0; i < 16; ++i) { tsum[t * 16 + i] = base; base += vals[i]; }
}

__global__ void k_scan3(const int* __restrict__ hist, const int* __restrict__ tsum,
                        int* __restrict__ rowptr, int* __restrict__ cursor,
                        int N, int CH, int E) {
    int t = blockIdx.x * blockDim.x + threadIdx.x;
    int a0 = t * CH;
    int a1 = a0 + CH; if (a1 > N) a1 = N;
    int run = tsum[t];
    for (int a = a0; a < a1; ++a) {
        rowptr[a] = run;
        cursor[a] = run;
        run += hist[a];
    }
    if (t == 0) rowptr[N] = E;
}

// ---- scatter pass: 8B scattered store {col, dist} into record slot ----
__global__ void k_scatter_cd(const int* __restrict__ ei, const float* __restrict__ pos,
                             int* __restrict__ cursor, uint4* __restrict__ recs,
                             int E, int N) {
    int i = blockIdx.x * blockDim.x + threadIdx.x;
    int stride = gridDim.x * blockDim.x;
    for (; i < E; i += stride) {
        int r = ei[i];
        int c = ei[E + i];
        r = ((unsigned)r < (unsigned)N) ? r : 0;
        c = ((unsigned)c < (unsigned)N) ? c : 0;
        float dx = pos[r * 3 + 0] - pos[c * 3 + 0];
        float dy = pos[r * 3 + 1] - pos[c * 3 + 1];
        float dz = pos[r * 3 + 2] - pos[c * 3 + 2];
        float dist = sqrtf(fmaf(dx, dx, fmaf(dy, dy, dz * dz)) + 1e-12f);
        int p = atomicAdd(&cursor[r], 1);
        uint2 cd;
        cd.x = (u32)c;
        cd.y = __float_as_uint(dist);
        ((uint2*)recs)[4 * (size_t)p] = cd;   // first 8B of recs[2p]
    }
}

// ---- streaming pass: expand {col, dist} -> full 32B record, in place ----
__global__ void k_build_recs(uint4* __restrict__ recs, int E) {
    int p = blockIdx.x * blockDim.x + threadIdx.x;
    int stride = gridDim.x * blockDim.x;
    for (; p < E; p += stride) {
        uint2 cd = ((const uint2*)recs)[4 * (size_t)p];
        float dist = __uint_as_float(cd.y);
        // centers = linspace(0,5,8), width = 5/7, scaling = 1/sqrt(2pi)
        u32 rb[R];
#pragma unroll
        for (int rr = 0; rr < R; ++rr) {
            float t = (dist - 0.71428573f * (float)rr) * 1.3999999f;
            rb[rr] = f2bf_bits(0.3989423f * __expf(-0.5f * t * t));
        }
        uint4 w0, w1;
        w0.x = cd.x;
        w0.y = cd.y;
        w0.z = rb[0] | (rb[1] << 16);
        w0.w = rb[2] | (rb[3] << 16);
        w1.x = rb[4] | (rb[5] << 16);
        w1.y = rb[6] | (rb[7] << 16);
        w1.z = 0u; w1.w = 0u;
        recs[2 * (size_t)p + 0] = w0;
        recs[2 * (size_t)p + 1] = w1;
    }
}

// h = b1 + sum_r rbf[r] * z[col][j][r]
__device__ __forceinline__ float edge_dot(uint4 r0, uint4 r1, uint4 zv, float b1j) {
    float h = b1j;
    h = fmaf(bflo(r0.z), bflo(zv.x), h);
    h = fmaf(bfhi(r0.z), bfhi(zv.x), h);
    h = fmaf(bflo(r0.w), bflo(zv.y), h);
    h = fmaf(bfhi(r0.w), bfhi(zv.y), h);
    h = fmaf(bflo(r1.x), bflo(zv.z), h);
    h = fmaf(bfhi(r1.x), bfhi(zv.z), h);
    h = fmaf(bflo(r1.y), bflo(zv.w), h);
    h = fmaf(bfhi(r1.y), bfhi(zv.w), h);
    return h;
}
__device__ __forceinline__ float silu_f(float h) {
    return h * __builtin_amdgcn_rcpf(1.f + __expf(-h));
}

// ---- per-row edge kernel: 32 lanes = one row; records pre-baked; fused epilogue ----
__global__ void k_edge_csr(const int* __restrict__ rowptr, const uint4* __restrict__ recs,
                           const __hip_bfloat16* __restrict__ z,
                           const float* __restrict__ x, const float* __restrict__ b1,
                           const float* __restrict__ W2, const float* __restrict__ b2,
                           float* __restrict__ out, int N) {
    __shared__ float W2s[C * C];
    for (int i = threadIdx.x; i < C * C; i += blockDim.x) W2s[i] = W2[i];
    __syncthreads();
    int gt = blockIdx.x * blockDim.x + threadIdx.x;
    int j = gt & 31;
    int n = gt >> 5;
    if (n >= N) return;
    int p0 = rowptr[n];
    int p1 = rowptr[n + 1];
    float b1j = b1[j];
    float acc = 0.f;
    int p = p0;
    for (; p + 4 <= p1; p += 4) {
        uint4 a0 = recs[2 * (size_t)p + 0], a1 = recs[2 * (size_t)p + 1];
        uint4 b0 = recs[2 * (size_t)p + 2], b1r = recs[2 * (size_t)p + 3];
        uint4 c0 = recs[2 * (size_t)p + 4], c1 = recs[2 * (size_t)p + 5];
        uint4 d0 = recs[2 * (size_t)p + 6], d1 = recs[2 * (size_t)p + 7];
        uint4 za = ((const uint4*)(z + (size_t)a0.x * (R * C)))[j];
        uint4 zb = ((const uint4*)(z + (size_t)b0.x * (R * C)))[j];
        uint4 zc = ((const uint4*)(z + (size_t)c0.x * (R * C)))[j];
        uint4 zd = ((const uint4*)(z + (size_t)d0.x * (R * C)))[j];
        float ha = edge_dot(a0, a1, za, b1j);
        float hb = edge_dot(b0, b1r, zb, b1j);
        float hc = edge_dot(c0, c1, zc, b1j);
        float hd = edge_dot(d0, d1, zd, b1j);
        acc += silu_f(ha) + silu_f(hb) + silu_f(hc) + silu_f(hd);
    }
    for (; p < p1; ++p) {
        uint4 a0 = recs[2 * (size_t)p + 0], a1 = recs[2 * (size_t)p + 1];
        uint4 za = ((const uint4*)(z + (size_t)a0.x * (R * C)))[j];
        acc += silu_f(edge_dot(a0, a1, za, b1j));
    }
    // epilogue: out[n][j] = x[n][j] + sum_i acc_i * W2[i][j] + deg * b2[j]
    float v = fmaf((float)(p1 - p0), b2[j], x[(size_t)n * C + j]);
#pragma unroll
    for (int i = 0; i < C; ++i)
        v = fmaf(__shfl(acc, i, 32), W2s[i * C + j], v);
    out[(size_t)n * C + j] = v;
}

// rbf for fallback tiers
__device__ __forceinline__ float rbf_lane(float dist, int r) {
    float t = (dist - 0.71428573f * (float)r) * 1.3999999f;
    return 0.3989423f * __expf(-0.5f * t * t);
}

// ---- Tier B kernels (proven fallback) ----
__global__ void k_edge_direct(const int* __restrict__ ei, const float* __restrict__ pos,
                              const float* __restrict__ x, const float* __restrict__ M,
                              const float* __restrict__ b1,
                              float* __restrict__ agg, float* __restrict__ deg,
                              int E, int N) {
    __shared__ float Ms[R * C * C];
    for (int i = threadIdx.x; i < R * C * C; i += blockDim.x) Ms[i] = M[i];
    __syncthreads();
    int gt = blockIdx.x * blockDim.x + threadIdx.x;
    int j = gt & 31;
    int g = gt >> 5;
    int ngroups = (gridDim.x * blockDim.x) >> 5;
    float b1j = b1[j];
    for (int e = g; e < E; e += ngroups) {
        int row = ei[e];
        int col = ei[E + e];
        row = ((unsigned)row < (unsigned)N) ? row : 0;
        col = ((unsigned)col < (unsigned)N) ? col : 0;
        float dx = pos[row * 3 + 0] - pos[col * 3 + 0];
        float dy = pos[row * 3 + 1] - pos[col * 3 + 1];
        float dz = pos[row * 3 + 2] - pos[col * 3 + 2];
        float dist = sqrtf(fmaf(dx, dx, fmaf(dy, dy, dz * dz)) + 1e-12f);
        float my_rbf = rbf_lane(dist, j & 7);
        float xr[C];
#pragma unroll
        for (int c = 0; c < C; ++c) xr[c] = x[(size_t)col * C + c];
        float h = b1j;
#pragma unroll
        for (int r = 0; r < R; ++r) {
            float s = 0.f;
#pragma unroll
            for (int c = 0; c < C; ++c)
                s = fmaf(xr[c], Ms[r * C * C + c * C + j], s);
            h = fmaf(__shfl(my_rbf, r, 32), s, h);
        }
        float sh = h / (1.f + __expf(-h));
        atomicAdd(&agg[(size_t)row * C + j], sh);
        if (j == 0) atomicAdd(&deg[row], 1.f);
    }
}

__global__ void k_final(const float* __restrict__ x, const float* __restrict__ agg,
                        const float* __restrict__ deg, const float* __restrict__ W2,
                        const float* __restrict__ b2, float* __restrict__ out,
                        int N) {
    int t = threadIdx.x;
    int j = t & 31;
    float w2[C];
#pragma unroll
    for (int i = 0; i < C; ++i) w2[i] = W2[i * C + j];
    float b2j = b2[j];
    int g = (blockIdx.x * blockDim.x + t) >> 5;
    int ngroups = (gridDim.x * blockDim.x) >> 5;
    for (int n = g; n < N; n += ngroups) {
        const float* ap = agg + (size_t)n * C;
        float acc = 0.f;
#pragma unroll
        for (int i = 0; i < C; ++i) acc = fmaf(ap[i], w2[i], acc);
        out[(size_t)n * C + j] = x[(size_t)n * C + j] + acc + deg[n] * b2j;
    }
}

// ---- Tier C (no usable ws) ----
__global__ void k_edge_full(const int* __restrict__ ei, const float* __restrict__ pos,
                            const float* __restrict__ x,
                            const float* __restrict__ Wtp, const float* __restrict__ W1,
                            const float* __restrict__ b1,
                            const float* __restrict__ W2, const float* __restrict__ b2,
                            float* __restrict__ out, int E, int N) {
    __shared__ float Ms[R * C * C];
    __shared__ float W2s[C * C];
    for (int idx = threadIdx.x; idx < R * C * C; idx += blockDim.x) {
        int r = idx >> 10, c = (idx >> 5) & 31, jj = idx & 31;
        float acc = 0.f;
#pragma unroll
        for (int o = 0; o < C; ++o)
            acc = fmaf(Wtp[c * R * C + r * C + o], W1[(r * C + o) * C + jj], acc);
        Ms[idx] = acc;
    }
    for (int idx = threadIdx.x; idx < C * C; idx += blockDim.x) W2s[idx] = W2[idx];
    __syncthreads();
    int gt = blockIdx.x * blockDim.x + threadIdx.x;
    int j = gt & 31;
    int g = gt >> 5;
    int ngroups = (gridDim.x * blockDim.x) >> 5;
    float b1j = b1[j];
    float b2j = b2[j];
    for (int e = g; e < E; e += ngroups) {
        int row = ei[e];
        int col = ei[E + e];
        row = ((unsigned)row < (unsigned)N) ? row : 0;
        col = ((unsigned)col < (unsigned)N) ? col : 0;
        float dx = pos[row * 3 + 0] - pos[col * 3 + 0];
        float dy = pos[row * 3 + 1] - pos[col * 3 + 1];
        float dz = pos[row * 3 + 2] - pos[col * 3 + 2];
        float dist = sqrtf(fmaf(dx, dx, fmaf(dy, dy, dz * dz)) + 1e-12f);
        float my_rbf = rbf_lane(dist, j & 7);
        float xr[C];
#pragma unroll
        for (int c = 0; c < C; ++c) xr[c] = x[(size_t)col * C + c];
        float h = b1j;
#pragma unroll
        for (int r = 0; r < R; ++r) {
            float s = 0.f;
#pragma unroll
            for (int c = 0; c < C; ++c)
                s = fmaf(xr[c], Ms[r * C * C + c * C + j], s);
            h = fmaf(__shfl(my_rbf, r, 32), s, h);
        }
        float sh = h / (1.f + __expf(-h));
        float v = b2j;
#pragma unroll
        for (int i = 0; i < C; ++i)
            v = fmaf(__shfl(sh, i, 32), W2s[i * C + j], v);
        atomicAdd(&out[(size_t)row * C + j], v);
    }
}

__global__ void k_add_x(const float* __restrict__ x, float* __restrict__ out, int total) {
    int i = blockIdx.x * blockDim.x + threadIdx.x;
    int stride = gridDim.x * blockDim.x;
    for (; i < total; i += stride) out[i] += x[i];
}

extern "C" void kernel_launch(void* const* d_in, const int* in_sizes, int n_in,
                              void* d_out, int out_size, void* d_ws, size_t ws_size,
                              hipStream_t stream) {
    const float* x   = (const float*)d_in[0];
    const float* pos = (const float*)d_in[1];
    const int*   ei  = (const int*)d_in[2];
    const float* Wtp = (const float*)d_in[3];
    const float* W1  = (const float*)d_in[4];
    const float* b1  = (const float*)d_in[5];
    const float* W2  = (const float*)d_in[6];
    const float* b2  = (const float*)d_in[7];
    int N = in_sizes[0] / C;
    int E = in_sizes[2] / 2;

    char* ws = (char*)d_ws;
    size_t mBytes   = (size_t)R * C * C * sizeof(float);              // 32 KB
    size_t zBytes   = (size_t)N * R * C * sizeof(__hip_bfloat16);     // 25.6 MB
    size_t histB    = (size_t)N * sizeof(int);
    size_t rowptrB  = (size_t)(N + 1) * sizeof(int);
    size_t cursorB  = (size_t)N * sizeof(int);
    size_t recsB    = (size_t)E * 32;                                 // 25.6 MB
    size_t tsumB    = (size_t)SCAN_G * sizeof(int);                   // 64 KB
    size_t aggBytes = (size_t)N * (C + 1) * sizeof(float);            // tier B
    size_t tierANeed = mBytes + zBytes + histB + rowptrB + cursorB + recsB + tsumB;
    bool tierA = ws_size >= tierANeed;
    bool tierB = !tierA && ws_size >= mBytes + aggBytes;

    if (tierA) {
        size_t off = 0;
        float*          M      = (float*)(ws + off); off += mBytes;
        __hip_bfloat16* z      = (__hip_bfloat16*)(ws + off); off += zBytes;
        int*            hist   = (int*)(ws + off); off += histB;
        int*            rowptr = (int*)(ws + off); off += rowptrB;
        int*            cursor = (int*)(ws + off); off += cursorB;
        uint4*          recs   = (uint4*)(ws + off); off += recsB;
        int*            tsum   = (int*)(ws + off);

        int CH = (N + SCAN_G - 1) / SCAN_G;
        hipMemsetAsync(hist, 0, histB, stream);
        k_prepM<<<(R * C * C + 255) / 256, 256, 0, stream>>>(Wtp, W1, M);
        k_nodeZ<<<(N + NPB - 1) / NPB, 256, 0, stream>>>(x, M, z, N);
        k_hist<<<(E + 255) / 256, 256, 0, stream>>>(ei, hist, E, N);
        k_scan1<<<SCAN_G / 256, 256, 0, stream>>>(hist, tsum, N, CH);
        k_scan2<<<1, 1024, 0, stream>>>(tsum);
        k_scan3<<<SCAN_G / 256, 256, 0, stream>>>(hist, tsum, rowptr, cursor, N, CH, E);
        k_scatter_cd<<<(E + 255) / 256, 256, 0, stream>>>(ei, pos, cursor, recs, E, N);
        k_build_recs<<<(E + 255) / 256, 256, 0, stream>>>(recs, E);
        int blocks = (int)(((size_t)N * 32 + 255) / 256);
        k_edge_csr<<<blocks, 256, 0, stream>>>(rowptr, recs, z, x, b1, W2, b2,
                                               (float*)d_out, N);
    } else if (tierB) {
        float* M   = (float*)ws;
        float* agg = (float*)(ws + mBytes);
        float* deg = agg + (size_t)N * C;
        hipMemsetAsync(agg, 0, aggBytes, stream);
        k_prepM<<<(R * C * C + 255) / 256, 256, 0, stream>>>(Wtp, W1, M);
        k_edge_direct<<<2048, 256, 0, stream>>>(ei, pos, x, M, b1, agg, deg, E, N);
        k_final<<<1024, 256, 0, stream>>>(x, agg, deg, W2, b2, (float*)d_out, N);
    } else {
        hipMemsetAsync(d_out, 0, (size_t)N * C * sizeof(float), stream);
        k_edge_full<<<1024, 256, 0, stream>>>(ei, pos, x, Wtp, W1, b1, W2, b2,
                                              (float*)d_out, E, N);
        k_add_x<<<1024, 256, 0, stream>>>(x, (float*)d_out, N * C);
    }
}

// Round 10
// 205.014 us; speedup vs baseline: 1.1552x; 1.0177x over previous
//
#include <hip/hip_runtime.h>
#include <hip/hip_bf16.h>

#define C 32
#define R 8
#define SCAN_G 16384   // 64 blocks x 256 threads
#define NPB 32         // nodes per block in k_nodeZ

typedef unsigned int u32;
__device__ __forceinline__ float bflo(u32 u) { return __uint_as_float(u << 16); }
__device__ __forceinline__ float bfhi(u32 u) { return __uint_as_float(u & 0xffff0000u); }
// f32 -> bf16 bits with round-to-nearest-even
__device__ __forceinline__ u32 f2bf_bits(float f) {
    u32 u = __float_as_uint(f);
    u32 lsb = (u >> 16) & 1u;
    return (u + 0x7fffu + lsb) >> 16;
}

// ---- M[r][c][j] = sum_o W_tp[c][r][o] * W1[r*C+o][j]   (f32, 32 KB) ----
__global__ void k_prepM(const float* __restrict__ Wtp, const float* __restrict__ W1,
                        float* __restrict__ M) {
    int idx = blockIdx.x * 256 + threadIdx.x;
    if (idx >= R * C * C) return;
    int r = idx >> 10;
    int c = (idx >> 5) & 31;
    int j = idx & 31;
    float acc = 0.f;
#pragma unroll
    for (int o = 0; o < C; ++o)
        acc = fmaf(Wtp[c * R * C + r * C + o], W1[(r * C + o) * C + j], acc);
    M[idx] = acc;
}

// ---- z[n][j][r] = sum_c x[n][c] * M[r][c][j]  (bf16; r contiguous), x via LDS ----
__global__ void k_nodeZ(const float* __restrict__ x, const float* __restrict__ M,
                        __hip_bfloat16* __restrict__ z, int N) {
    __shared__ float xs[NPB * C];
    int t = threadIdx.x;
    int n0 = blockIdx.x * NPB;
    for (int i = t * 4; i < NPB * C; i += 256 * 4) {
        size_t gbase = (size_t)n0 * C + i;
        float4 v = make_float4(0.f, 0.f, 0.f, 0.f);
        if (gbase + 3 < (size_t)N * C) v = *(const float4*)(x + gbase);
        *(float4*)(xs + i) = v;
    }
    __syncthreads();
    int r = t & 7, j = t >> 3;
    float m[C];
#pragma unroll
    for (int c = 0; c < C; ++c) m[c] = M[r * C * C + c * C + j];
    int nmax = N - n0; if (nmax > NPB) nmax = NPB;
    for (int nn = 0; nn < nmax; ++nn) {
        const float* xp = xs + nn * C;
        float acc = 0.f;
#pragma unroll
        for (int c = 0; c < C; ++c) acc = fmaf(xp[c], m[c], acc);
        z[(size_t)(n0 + nn) * (R * C) + t] = __float2bfloat16(acc);
    }
}

// ---- CSR build ----
__global__ void k_hist(const int* __restrict__ ei, int* __restrict__ hist, int E, int N) {
    int i = blockIdx.x * blockDim.x + threadIdx.x;
    int stride = gridDim.x * blockDim.x;
    for (; i < E; i += stride) {
        int r = ei[i];
        r = ((unsigned)r < (unsigned)N) ? r : 0;
        atomicAdd(&hist[r], 1);
    }
}

__global__ void k_scan1(const int* __restrict__ hist, int* __restrict__ tsum,
                        int N, int CH) {
    int t = blockIdx.x * blockDim.x + threadIdx.x;
    int a0 = t * CH;
    int a1 = a0 + CH; if (a1 > N) a1 = N;
    int s = 0;
    for (int a = a0; a < a1; ++a) s += hist[a];
    tsum[t] = s;
}

__global__ void k_scan2(int* __restrict__ tsum) {
    __shared__ int s[1024];
    int t = threadIdx.x;
    int vals[16];
    int sum = 0;
#pragma unroll
    for (int i = 0; i < 16; ++i) { vals[i] = tsum[t * 16 + i]; sum += vals[i]; }
    s[t] = sum;
    __syncthreads();
    for (int off = 1; off < 1024; off <<= 1) {
        int v = (t >= off) ? s[t - off] : 0;
        __syncthreads();
        s[t] += v;
        __syncthreads();
    }
    int base = (t == 0) ? 0 : s[t - 1];
#pragma unroll
    for (int i = 0; i < 16; ++i) { tsum[t * 16 + i] = base; base += vals[i]; }
}

__global__ void k_scan3(const int* __restrict__ hist, const int* __restrict__ tsum,
                        int* __restrict__ rowptr, int* __restrict__ cursor,
                        int N, int CH, int E) {
    int t = blockIdx.x * blockDim.x + threadIdx.x;
    int a0 = t * CH;
    int a1 = a0 + CH; if (a1 > N) a1 = N;
    int run = tsum[t];
    for (int a = a0; a < a1; ++a) {
        rowptr[a] = run;
        cursor[a] = run;
        run += hist[a];
    }
    if (t == 0) rowptr[N] = E;
}

// ---- scatter pass: dense 8B scattered store {col, dist} ----
__global__ void k_scatter_cd(const int* __restrict__ ei, const float* __restrict__ pos,
                             int* __restrict__ cursor, uint2* __restrict__ cd,
                             int E, int N) {
    int i = blockIdx.x * blockDim.x + threadIdx.x;
    int stride = gridDim.x * blockDim.x;
    for (; i < E; i += stride) {
        int r = ei[i];
        int c = ei[E + i];
        r = ((unsigned)r < (unsigned)N) ? r : 0;
        c = ((unsigned)c < (unsigned)N) ? c : 0;
        float dx = pos[r * 3 + 0] - pos[c * 3 + 0];
        float dy = pos[r * 3 + 1] - pos[c * 3 + 1];
        float dz = pos[r * 3 + 2] - pos[c * 3 + 2];
        float dist = sqrtf(fmaf(dx, dx, fmaf(dy, dy, dz * dz)) + 1e-12f);
        int p = atomicAdd(&cursor[r], 1);
        uint2 v;
        v.x = (u32)c;
        v.y = __float_as_uint(dist);
        cd[p] = v;
    }
}

// ---- streaming pass: rbfs[p] = 8 x bf16 rbf from cd[p].dist, fully coalesced ----
__global__ void k_build_recs(const uint2* __restrict__ cd, uint4* __restrict__ rbfs, int E) {
    int p = blockIdx.x * blockDim.x + threadIdx.x;
    int stride = gridDim.x * blockDim.x;
    for (; p < E; p += stride) {
        float dist = __uint_as_float(cd[p].y);
        // centers = linspace(0,5,8), width = 5/7, scaling = 1/sqrt(2pi)
        u32 rb[R];
#pragma unroll
        for (int rr = 0; rr < R; ++rr) {
            float t = (dist - 0.71428573f * (float)rr) * 1.3999999f;
            rb[rr] = f2bf_bits(0.3989423f * __expf(-0.5f * t * t));
        }
        uint4 w;
        w.x = rb[0] | (rb[1] << 16);
        w.y = rb[2] | (rb[3] << 16);
        w.z = rb[4] | (rb[5] << 16);
        w.w = rb[6] | (rb[7] << 16);
        rbfs[p] = w;
    }
}

// h = b1 + sum_r rbf[r] * z[col][j][r]
__device__ __forceinline__ float edge_dot(uint4 rb, uint4 zv, float b1j) {
    float h = b1j;
    h = fmaf(bflo(rb.x), bflo(zv.x), h);
    h = fmaf(bfhi(rb.x), bfhi(zv.x), h);
    h = fmaf(bflo(rb.y), bflo(zv.y), h);
    h = fmaf(bfhi(rb.y), bfhi(zv.y), h);
    h = fmaf(bflo(rb.z), bflo(zv.z), h);
    h = fmaf(bfhi(rb.z), bfhi(zv.z), h);
    h = fmaf(bflo(rb.w), bflo(zv.w), h);
    h = fmaf(bfhi(rb.w), bfhi(zv.w), h);
    return h;
}
__device__ __forceinline__ float silu_f(float h) {
    return h * __builtin_amdgcn_rcpf(1.f + __expf(-h));
}

// ---- per-row edge kernel: 32 lanes = one row; fused epilogue ----
__global__ void k_edge_csr(const int* __restrict__ rowptr, const uint2* __restrict__ cd,
                           const uint4* __restrict__ rbfs,
                           const __hip_bfloat16* __restrict__ z,
                           const float* __restrict__ x, const float* __restrict__ b1,
                           const float* __restrict__ W2, const float* __restrict__ b2,
                           float* __restrict__ out, int N) {
    __shared__ float W2s[C * C];
    for (int i = threadIdx.x; i < C * C; i += blockDim.x) W2s[i] = W2[i];
    __syncthreads();
    int gt = blockIdx.x * blockDim.x + threadIdx.x;
    int j = gt & 31;
    int n = gt >> 5;
    if (n >= N) return;
    int p0 = rowptr[n];
    int p1 = rowptr[n + 1];
    float b1j = b1[j];
    float acc = 0.f;
    int p = p0;
    for (; p + 4 <= p1; p += 4) {
        u32 ca = cd[p + 0].x;
        u32 cb = cd[p + 1].x;
        u32 cc = cd[p + 2].x;
        u32 cdd = cd[p + 3].x;
        uint4 ra = rbfs[p + 0];
        uint4 rb = rbfs[p + 1];
        uint4 rc = rbfs[p + 2];
        uint4 rd = rbfs[p + 3];
        uint4 za = ((const uint4*)(z + (size_t)ca * (R * C)))[j];
        uint4 zb = ((const uint4*)(z + (size_t)cb * (R * C)))[j];
        uint4 zc = ((const uint4*)(z + (size_t)cc * (R * C)))[j];
        uint4 zd = ((const uint4*)(z + (size_t)cdd * (R * C)))[j];
        float ha = edge_dot(ra, za, b1j);
        float hb = edge_dot(rb, zb, b1j);
        float hc = edge_dot(rc, zc, b1j);
        float hd = edge_dot(rd, zd, b1j);
        acc += silu_f(ha) + silu_f(hb) + silu_f(hc) + silu_f(hd);
    }
    for (; p < p1; ++p) {
        u32 ca = cd[p].x;
        uint4 ra = rbfs[p];
        uint4 za = ((const uint4*)(z + (size_t)ca * (R * C)))[j];
        acc += silu_f(edge_dot(ra, za, b1j));
    }
    // epilogue: out[n][j] = x[n][j] + sum_i acc_i * W2[i][j] + deg * b2[j]
    float v = fmaf((float)(p1 - p0), b2[j], x[(size_t)n * C + j]);
#pragma unroll
    for (int i = 0; i < C; ++i)
        v = fmaf(__shfl(acc, i, 32), W2s[i * C + j], v);
    out[(size_t)n * C + j] = v;
}

// rbf for fallback tiers
__device__ __forceinline__ float rbf_lane(float dist, int r) {
    float t = (dist - 0.71428573f * (float)r) * 1.3999999f;
    return 0.3989423f * __expf(-0.5f * t * t);
}

// ---- Tier B kernels (proven fallback) ----
__global__ void k_edge_direct(const int* __restrict__ ei, const float* __restrict__ pos,
                              const float* __restrict__ x, const float* __restrict__ M,
                              const float* __restrict__ b1,
                              float* __restrict__ agg, float* __restrict__ deg,
                              int E, int N) {
    __shared__ float Ms[R * C * C];
    for (int i = threadIdx.x; i < R * C * C; i += blockDim.x) Ms[i] = M[i];
    __syncthreads();
    int gt = blockIdx.x * blockDim.x + threadIdx.x;
    int j = gt & 31;
    int g = gt >> 5;
    int ngroups = (gridDim.x * blockDim.x) >> 5;
    float b1j = b1[j];
    for (int e = g; e < E; e += ngroups) {
        int row = ei[e];
        int col = ei[E + e];
        row = ((unsigned)row < (unsigned)N) ? row : 0;
        col = ((unsigned)col < (unsigned)N) ? col : 0;
        float dx = pos[row * 3 + 0] - pos[col * 3 + 0];
        float dy = pos[row * 3 + 1] - pos[col * 3 + 1];
        float dz = pos[row * 3 + 2] - pos[col * 3 + 2];
        float dist = sqrtf(fmaf(dx, dx, fmaf(dy, dy, dz * dz)) + 1e-12f);
        float my_rbf = rbf_lane(dist, j & 7);
        float xr[C];
#pragma unroll
        for (int c = 0; c < C; ++c) xr[c] = x[(size_t)col * C + c];
        float h = b1j;
#pragma unroll
        for (int r = 0; r < R; ++r) {
            float s = 0.f;
#pragma unroll
            for (int c = 0; c < C; ++c)
                s = fmaf(xr[c], Ms[r * C * C + c * C + j], s);
            h = fmaf(__shfl(my_rbf, r, 32), s, h);
        }
        float sh = h / (1.f + __expf(-h));
        atomicAdd(&agg[(size_t)row * C + j], sh);
        if (j == 0) atomicAdd(&deg[row], 1.f);
    }
}

__global__ void k_final(const float* __restrict__ x, const float* __restrict__ agg,
                        const float* __restrict__ deg, const float* __restrict__ W2,
                        const float* __restrict__ b2, float* __restrict__ out,
                        int N) {
    int t = threadIdx.x;
    int j = t & 31;
    float w2[C];
#pragma unroll
    for (int i = 0; i < C; ++i) w2[i] = W2[i * C + j];
    float b2j = b2[j];
    int g = (blockIdx.x * blockDim.x + t) >> 5;
    int ngroups = (gridDim.x * blockDim.x) >> 5;
    for (int n = g; n < N; n += ngroups) {
        const float* ap = agg + (size_t)n * C;
        float acc = 0.f;
#pragma unroll
        for (int i = 0; i < C; ++i) acc = fmaf(ap[i], w2[i], acc);
        out[(size_t)n * C + j] = x[(size_t)n * C + j] + acc + deg[n] * b2j;
    }
}

// ---- Tier C (no usable ws) ----
__global__ void k_edge_full(const int* __restrict__ ei, const float* __restrict__ pos,
                            const float* __restrict__ x,
                            const float* __restrict__ Wtp, const float* __restrict__ W1,
                            const float* __restrict__ b1,
                            const float* __restrict__ W2, const float* __restrict__ b2,
                            float* __restrict__ out, int E, int N) {
    __shared__ float Ms[R * C * C];
    __shared__ float W2s[C * C];
    for (int idx = threadIdx.x; idx < R * C * C; idx += blockDim.x) {
        int r = idx >> 10, c = (idx >> 5) & 31, jj = idx & 31;
        float acc = 0.f;
#pragma unroll
        for (int o = 0; o < C; ++o)
            acc = fmaf(Wtp[c * R * C + r * C + o], W1[(r * C + o) * C + jj], acc);
        Ms[idx] = acc;
    }
    for (int idx = threadIdx.x; idx < C * C; idx += blockDim.x) W2s[idx] = W2[idx];
    __syncthreads();
    int gt = blockIdx.x * blockDim.x + threadIdx.x;
    int j = gt & 31;
    int g = gt >> 5;
    int ngroups = (gridDim.x * blockDim.x) >> 5;
    float b1j = b1[j];
    float b2j = b2[j];
    for (int e = g; e < E; e += ngroups) {
        int row = ei[e];
        int col = ei[E + e];
        row = ((unsigned)row < (unsigned)N) ? row : 0;
        col = ((unsigned)col < (unsigned)N) ? col : 0;
        float dx = pos[row * 3 + 0] - pos[col * 3 + 0];
        float dy = pos[row * 3 + 1] - pos[col * 3 + 1];
        float dz = pos[row * 3 + 2] - pos[col * 3 + 2];
        float dist = sqrtf(fmaf(dx, dx, fmaf(dy, dy, dz * dz)) + 1e-12f);
        float my_rbf = rbf_lane(dist, j & 7);
        float xr[C];
#pragma unroll
        for (int c = 0; c < C; ++c) xr[c] = x[(size_t)col * C + c];
        float h = b1j;
#pragma unroll
        for (int r = 0; r < R; ++r) {
            float s = 0.f;
#pragma unroll
            for (int c = 0; c < C; ++c)
                s = fmaf(xr[c], Ms[r * C * C + c * C + j], s);
            h = fmaf(__shfl(my_rbf, r, 32), s, h);
        }
        float sh = h / (1.f + __expf(-h));
        float v = b2j;
#pragma unroll
        for (int i = 0; i < C; ++i)
            v = fmaf(__shfl(sh, i, 32), W2s[i * C + j], v);
        atomicAdd(&out[(size_t)row * C + j], v);
    }
}

__global__ void k_add_x(const float* __restrict__ x, float* __restrict__ out, int total) {
    int i = blockIdx.x * blockDim.x + threadIdx.x;
    int stride = gridDim.x * blockDim.x;
    for (; i < total; i += stride) out[i] += x[i];
}

extern "C" void kernel_launch(void* const* d_in, const int* in_sizes, int n_in,
                              void* d_out, int out_size, void* d_ws, size_t ws_size,
                              hipStream_t stream) {
    const float* x   = (const float*)d_in[0];
    const float* pos = (const float*)d_in[1];
    const int*   ei  = (const int*)d_in[2];
    const float* Wtp = (const float*)d_in[3];
    const float* W1  = (const float*)d_in[4];
    const float* b1  = (const float*)d_in[5];
    const float* W2  = (const float*)d_in[6];
    const float* b2  = (const float*)d_in[7];
    int N = in_sizes[0] / C;
    int E = in_sizes[2] / 2;

    char* ws = (char*)d_ws;
    size_t mBytes   = (size_t)R * C * C * sizeof(float);              // 32 KB
    size_t zBytes   = (size_t)N * R * C * sizeof(__hip_bfloat16);     // 25.6 MB
    size_t histB    = (size_t)N * sizeof(int);
    size_t rowptrB  = (size_t)(N + 1) * sizeof(int);
    size_t cursorB  = (size_t)N * sizeof(int);
    size_t cdB      = (size_t)E * 8;                                  // 6.4 MB
    size_t rbfsB    = (size_t)E * 16;                                 // 12.8 MB
    size_t tsumB    = (size_t)SCAN_G * sizeof(int);                   // 64 KB
    size_t aggBytes = (size_t)N * (C + 1) * sizeof(float);            // tier B
    size_t tierANeed = mBytes + zBytes + histB + rowptrB + cursorB + cdB + rbfsB + tsumB;
    bool tierA = ws_size >= tierANeed;
    bool tierB = !tierA && ws_size >= mBytes + aggBytes;

    if (tierA) {
        size_t off = 0;
        float*          M      = (float*)(ws + off); off += mBytes;
        __hip_bfloat16* z      = (__hip_bfloat16*)(ws + off); off += zBytes;
        int*            hist   = (int*)(ws + off); off += histB;
        int*            rowptr = (int*)(ws + off); off += rowptrB;
        int*            cursor = (int*)(ws + off); off += cursorB;
        uint2*          cd     = (uint2*)(ws + off); off += cdB;
        uint4*          rbfs   = (uint4*)(ws + off); off += rbfsB;
        int*            tsum   = (int*)(ws + off);

        int CH = (N + SCAN_G - 1) / SCAN_G;
        hipMemsetAsync(hist, 0, histB, stream);
        k_prepM<<<(R * C * C + 255) / 256, 256, 0, stream>>>(Wtp, W1, M);
        k_nodeZ<<<(N + NPB - 1) / NPB, 256, 0, stream>>>(x, M, z, N);
        k_hist<<<(E + 255) / 256, 256, 0, stream>>>(ei, hist, E, N);
        k_scan1<<<SCAN_G / 256, 256, 0, stream>>>(hist, tsum, N, CH);
        k_scan2<<<1, 1024, 0, stream>>>(tsum);
        k_scan3<<<SCAN_G / 256, 256, 0, stream>>>(hist, tsum, rowptr, cursor, N, CH, E);
        k_scatter_cd<<<(E + 255) / 256, 256, 0, stream>>>(ei, pos, cursor, cd, E, N);
        k_build_recs<<<(E + 255) / 256, 256, 0, stream>>>(cd, rbfs, E);
        int blocks = (int)(((size_t)N * 32 + 255) / 256);
        k_edge_csr<<<blocks, 256, 0, stream>>>(rowptr, cd, rbfs, z, x, b1, W2, b2,
                                               (float*)d_out, N);
    } else if (tierB) {
        float* M   = (float*)ws;
        float* agg = (float*)(ws + mBytes);
        float* deg = agg + (size_t)N * C;
        hipMemsetAsync(agg, 0, aggBytes, stream);
        k_prepM<<<(R * C * C + 255) / 256, 256, 0, stream>>>(Wtp, W1, M);
        k_edge_direct<<<2048, 256, 0, stream>>>(ei, pos, x, M, b1, agg, deg, E, N);
        k_final<<<1024, 256, 0, stream>>>(x, agg, deg, W2, b2, (float*)d_out, N);
    } else {
        hipMemsetAsync(d_out, 0, (size_t)N * C * sizeof(float), stream);
        k_edge_full<<<1024, 256, 0, stream>>>(ei, pos, x, Wtp, W1, b1, W2, b2,
                                              (float*)d_out, E, N);
        k_add_x<<<1024, 256, 0, stream>>>(x, (float*)d_out, N * C);
    }
}

// Round 11
// 156.152 us; speedup vs baseline: 1.5167x; 1.3129x over previous
//
#include <hip/hip_runtime.h>
#include <hip/hip_bf16.h>

#define C 32
#define R 8
#define NPB 32        // nodes per block in nodeZ part
#define K_ELL 32      // ELL slots per row
#define OVF_CAP 65536

typedef unsigned int u32;
__device__ __forceinline__ float bflo(u32 u) { return __uint_as_float(u << 16); }
__device__ __forceinline__ float bfhi(u32 u) { return __uint_as_float(u & 0xffff0000u); }
__device__ __forceinline__ u32 f2bf_bits(float f) {
    u32 u = __float_as_uint(f);
    u32 lsb = (u >> 16) & 1u;
    return (u + 0x7fffu + lsb) >> 16;
}

// ---- M[r][c][j] = sum_o W_tp[c][r][o] * W1[r*C+o][j]   (f32, 32 KB) ----
__global__ void k_prepM(const float* __restrict__ Wtp, const float* __restrict__ W1,
                        float* __restrict__ M) {
    int idx = blockIdx.x * 256 + threadIdx.x;
    if (idx >= R * C * C) return;
    int r = idx >> 10;
    int c = (idx >> 5) & 31;
    int j = idx & 31;
    float acc = 0.f;
#pragma unroll
    for (int o = 0; o < C; ++o)
        acc = fmaf(Wtp[c * R * C + r * C + o], W1[(r * C + o) * C + j], acc);
    M[idx] = acc;
}

// ---- fused: blocks [0,ZB): nodeZ   |   blocks [ZB,..): per-edge scatter ----
// nodeZ: z[n][j][r] = sum_c x[n][c]*M[r][c][j] (bf16, r contiguous)
// scatter: rbfs[i]=8xbf16 rbf (coalesced); ell[row*32+local]={col,i}; overflow list
__global__ void k_fused(const float* __restrict__ x, const float* __restrict__ M,
                        __hip_bfloat16* __restrict__ z,
                        const int* __restrict__ ei, const float* __restrict__ pos,
                        int* __restrict__ cnt, int* __restrict__ ovfcnt,
                        uint4* __restrict__ ovf, uint4* __restrict__ rbfs,
                        uint2* __restrict__ ell, int N, int E, int ZB) {
    __shared__ float xs[NPB * C];
    int t = threadIdx.x;
    if ((int)blockIdx.x < ZB) {
        int n0 = blockIdx.x * NPB;
        for (int i = t * 4; i < NPB * C; i += 256 * 4) {
            size_t gbase = (size_t)n0 * C + i;
            float4 v = make_float4(0.f, 0.f, 0.f, 0.f);
            if (gbase + 3 < (size_t)N * C) v = *(const float4*)(x + gbase);
            *(float4*)(xs + i) = v;
        }
        __syncthreads();
        int r = t & 7, j = t >> 3;
        float m[C];
#pragma unroll
        for (int c = 0; c < C; ++c) m[c] = M[r * C * C + c * C + j];
        int nmax = N - n0; if (nmax > NPB) nmax = NPB;
        for (int nn = 0; nn < nmax; ++nn) {
            const float* xp = xs + nn * C;
            float acc = 0.f;
#pragma unroll
            for (int c = 0; c < C; ++c) acc = fmaf(xp[c], m[c], acc);
            z[(size_t)(n0 + nn) * (R * C) + t] = __float2bfloat16(acc);
        }
    } else {
        int i = (blockIdx.x - ZB) * 256 + t;
        if (i < E) {
            int r = ei[i];
            int c = ei[E + i];
            r = ((unsigned)r < (unsigned)N) ? r : 0;
            c = ((unsigned)c < (unsigned)N) ? c : 0;
            float dx = pos[r * 3 + 0] - pos[c * 3 + 0];
            float dy = pos[r * 3 + 1] - pos[c * 3 + 1];
            float dz = pos[r * 3 + 2] - pos[c * 3 + 2];
            float dist = sqrtf(fmaf(dx, dx, fmaf(dy, dy, dz * dz)) + 1e-12f);
            // centers = linspace(0,5,8), width=5/7, scaling=1/sqrt(2pi)
            u32 rb[R];
#pragma unroll
            for (int rr = 0; rr < R; ++rr) {
                float tt = (dist - 0.71428573f * (float)rr) * 1.3999999f;
                rb[rr] = f2bf_bits(0.3989423f * __expf(-0.5f * tt * tt));
            }
            uint4 w;
            w.x = rb[0] | (rb[1] << 16);
            w.y = rb[2] | (rb[3] << 16);
            w.z = rb[4] | (rb[5] << 16);
            w.w = rb[6] | (rb[7] << 16);
            rbfs[i] = w;                        // coalesced by edge id
            int local = atomicAdd(&cnt[r], 1);
            if (local < K_ELL) {
                uint2 v;
                v.x = (u32)c;
                v.y = (u32)i;
                ell[(size_t)r * K_ELL + local] = v;
            } else {
                int q = atomicAdd(ovfcnt, 1);
                if (q < OVF_CAP) ovf[q] = make_uint4((u32)r, (u32)c, (u32)i, 0u);
            }
        }
    }
}

// h = b1 + sum_r rbf[r] * z[col][j][r]
__device__ __forceinline__ float edge_dot(uint4 rb, uint4 zv, float b1j) {
    float h = b1j;
    h = fmaf(bflo(rb.x), bflo(zv.x), h);
    h = fmaf(bfhi(rb.x), bfhi(zv.x), h);
    h = fmaf(bflo(rb.y), bflo(zv.y), h);
    h = fmaf(bfhi(rb.y), bfhi(zv.y), h);
    h = fmaf(bflo(rb.z), bflo(zv.z), h);
    h = fmaf(bfhi(rb.z), bfhi(zv.z), h);
    h = fmaf(bflo(rb.w), bflo(zv.w), h);
    h = fmaf(bfhi(rb.w), bfhi(zv.w), h);
    return h;
}
__device__ __forceinline__ float silu_f(float h) {
    return h * __builtin_amdgcn_rcpf(1.f + __expf(-h));
}

// ---- per-row ELL edge kernel: 32 lanes = one row; fused W2/b2 epilogue ----
__global__ void k_edge_ell(const int* __restrict__ cnt, const uint2* __restrict__ ell,
                           const uint4* __restrict__ rbfs,
                           const __hip_bfloat16* __restrict__ z,
                           const float* __restrict__ x, const float* __restrict__ b1,
                           const float* __restrict__ W2, const float* __restrict__ b2,
                           float* __restrict__ out, int N) {
    __shared__ float W2s[C * C];
    for (int i = threadIdx.x; i < C * C; i += blockDim.x) W2s[i] = W2[i];
    __syncthreads();
    int gt = blockIdx.x * blockDim.x + threadIdx.x;
    int j = gt & 31;
    int n = gt >> 5;
    if (n >= N) return;
    int deg = cnt[n];
    int m = deg < K_ELL ? deg : K_ELL;
    uint2 pair = make_uint2(0u, 0u);
    if (j < m) pair = ell[(size_t)n * K_ELL + j];
    float b1j = b1[j];
    float acc = 0.f;
    int base = 0;
    for (; base + 4 <= m; base += 4) {
        u32 c0 = __shfl(pair.x, base + 0, 32), e0 = __shfl(pair.y, base + 0, 32);
        u32 c1 = __shfl(pair.x, base + 1, 32), e1 = __shfl(pair.y, base + 1, 32);
        u32 c2 = __shfl(pair.x, base + 2, 32), e2 = __shfl(pair.y, base + 2, 32);
        u32 c3 = __shfl(pair.x, base + 3, 32), e3 = __shfl(pair.y, base + 3, 32);
        uint4 r0 = rbfs[e0];
        uint4 r1 = rbfs[e1];
        uint4 r2 = rbfs[e2];
        uint4 r3 = rbfs[e3];
        uint4 z0 = ((const uint4*)(z + (size_t)c0 * (R * C)))[j];
        uint4 z1 = ((const uint4*)(z + (size_t)c1 * (R * C)))[j];
        uint4 z2 = ((const uint4*)(z + (size_t)c2 * (R * C)))[j];
        uint4 z3 = ((const uint4*)(z + (size_t)c3 * (R * C)))[j];
        float h0 = edge_dot(r0, z0, b1j);
        float h1 = edge_dot(r1, z1, b1j);
        float h2 = edge_dot(r2, z2, b1j);
        float h3 = edge_dot(r3, z3, b1j);
        acc += silu_f(h0) + silu_f(h1) + silu_f(h2) + silu_f(h3);
    }
    for (; base < m; ++base) {
        u32 c0 = __shfl(pair.x, base, 32), e0 = __shfl(pair.y, base, 32);
        uint4 r0 = rbfs[e0];
        uint4 z0 = ((const uint4*)(z + (size_t)c0 * (R * C)))[j];
        acc += silu_f(edge_dot(r0, z0, b1j));
    }
    // out[n][j] = x[n][j] + sum_i acc_i*W2[i][j] + deg*b2[j]   (deg = TRUE degree)
    float v = fmaf((float)deg, b2[j], x[(size_t)n * C + j]);
#pragma unroll
    for (int i = 0; i < C; ++i)
        v = fmaf(__shfl(acc, i, 32), W2s[i * C + j], v);
    out[(size_t)n * C + j] = v;
}

// ---- overflow fix-up: add W2-weighted silu of overflow edges (b2 already counted) ----
__global__ void k_overflow(const int* __restrict__ ovfcnt, const uint4* __restrict__ ovf,
                           const uint4* __restrict__ rbfs,
                           const __hip_bfloat16* __restrict__ z,
                           const float* __restrict__ b1, const float* __restrict__ W2,
                           float* __restrict__ out, int N) {
    int novf = ovfcnt[0];
    if (novf > OVF_CAP) novf = OVF_CAP;
    int gt = blockIdx.x * blockDim.x + threadIdx.x;
    int j = gt & 31;
    int g = gt >> 5;
    int ngroups = (gridDim.x * blockDim.x) >> 5;
    for (int q = g; q < novf; q += ngroups) {
        uint4 rec = ovf[q];
        u32 row = rec.x, col = rec.y, eid = rec.z;
        uint4 rb = rbfs[eid];
        uint4 zv = ((const uint4*)(z + (size_t)col * (R * C)))[j];
        float sh = silu_f(edge_dot(rb, zv, b1[j]));
        float v = 0.f;
#pragma unroll
        for (int i = 0; i < C; ++i)
            v = fmaf(__shfl(sh, i, 32), W2[i * C + j], v);
        atomicAdd(&out[(size_t)row * C + j], v);
    }
}

// rbf for fallback tiers
__device__ __forceinline__ float rbf_lane(float dist, int r) {
    float t = (dist - 0.71428573f * (float)r) * 1.3999999f;
    return 0.3989423f * __expf(-0.5f * t * t);
}

// ---- Tier B kernels (proven fallback) ----
__global__ void k_edge_direct(const int* __restrict__ ei, const float* __restrict__ pos,
                              const float* __restrict__ x, const float* __restrict__ M,
                              const float* __restrict__ b1,
                              float* __restrict__ agg, float* __restrict__ deg,
                              int E, int N) {
    __shared__ float Ms[R * C * C];
    for (int i = threadIdx.x; i < R * C * C; i += blockDim.x) Ms[i] = M[i];
    __syncthreads();
    int gt = blockIdx.x * blockDim.x + threadIdx.x;
    int j = gt & 31;
    int g = gt >> 5;
    int ngroups = (gridDim.x * blockDim.x) >> 5;
    float b1j = b1[j];
    for (int e = g; e < E; e += ngroups) {
        int row = ei[e];
        int col = ei[E + e];
        row = ((unsigned)row < (unsigned)N) ? row : 0;
        col = ((unsigned)col < (unsigned)N) ? col : 0;
        float dx = pos[row * 3 + 0] - pos[col * 3 + 0];
        float dy = pos[row * 3 + 1] - pos[col * 3 + 1];
        float dz = pos[row * 3 + 2] - pos[col * 3 + 2];
        float dist = sqrtf(fmaf(dx, dx, fmaf(dy, dy, dz * dz)) + 1e-12f);
        float my_rbf = rbf_lane(dist, j & 7);
        float xr[C];
#pragma unroll
        for (int c = 0; c < C; ++c) xr[c] = x[(size_t)col * C + c];
        float h = b1j;
#pragma unroll
        for (int r = 0; r < R; ++r) {
            float s = 0.f;
#pragma unroll
            for (int c = 0; c < C; ++c)
                s = fmaf(xr[c], Ms[r * C * C + c * C + j], s);
            h = fmaf(__shfl(my_rbf, r, 32), s, h);
        }
        float sh = h / (1.f + __expf(-h));
        atomicAdd(&agg[(size_t)row * C + j], sh);
        if (j == 0) atomicAdd(&deg[row], 1.f);
    }
}

__global__ void k_final(const float* __restrict__ x, const float* __restrict__ agg,
                        const float* __restrict__ deg, const float* __restrict__ W2,
                        const float* __restrict__ b2, float* __restrict__ out,
                        int N) {
    int t = threadIdx.x;
    int j = t & 31;
    float w2[C];
#pragma unroll
    for (int i = 0; i < C; ++i) w2[i] = W2[i * C + j];
    float b2j = b2[j];
    int g = (blockIdx.x * blockDim.x + t) >> 5;
    int ngroups = (gridDim.x * blockDim.x) >> 5;
    for (int n = g; n < N; n += ngroups) {
        const float* ap = agg + (size_t)n * C;
        float acc = 0.f;
#pragma unroll
        for (int i = 0; i < C; ++i) acc = fmaf(ap[i], w2[i], acc);
        out[(size_t)n * C + j] = x[(size_t)n * C + j] + acc + deg[n] * b2j;
    }
}

// ---- Tier C (no usable ws) ----
__global__ void k_edge_full(const int* __restrict__ ei, const float* __restrict__ pos,
                            const float* __restrict__ x,
                            const float* __restrict__ Wtp, const float* __restrict__ W1,
                            const float* __restrict__ b1,
                            const float* __restrict__ W2, const float* __restrict__ b2,
                            float* __restrict__ out, int E, int N) {
    __shared__ float Ms[R * C * C];
    __shared__ float W2s[C * C];
    for (int idx = threadIdx.x; idx < R * C * C; idx += blockDim.x) {
        int r = idx >> 10, c = (idx >> 5) & 31, jj = idx & 31;
        float acc = 0.f;
#pragma unroll
        for (int o = 0; o < C; ++o)
            acc = fmaf(Wtp[c * R * C + r * C + o], W1[(r * C + o) * C + jj], acc);
        Ms[idx] = acc;
    }
    for (int idx = threadIdx.x; idx < C * C; idx += blockDim.x) W2s[idx] = W2[idx];
    __syncthreads();
    int gt = blockIdx.x * blockDim.x + threadIdx.x;
    int j = gt & 31;
    int g = gt >> 5;
    int ngroups = (gridDim.x * blockDim.x) >> 5;
    float b1j = b1[j];
    float b2j = b2[j];
    for (int e = g; e < E; e += ngroups) {
        int row = ei[e];
        int col = ei[E + e];
        row = ((unsigned)row < (unsigned)N) ? row : 0;
        col = ((unsigned)col < (unsigned)N) ? col : 0;
        float dx = pos[row * 3 + 0] - pos[col * 3 + 0];
        float dy = pos[row * 3 + 1] - pos[col * 3 + 1];
        float dz = pos[row * 3 + 2] - pos[col * 3 + 2];
        float dist = sqrtf(fmaf(dx, dx, fmaf(dy, dy, dz * dz)) + 1e-12f);
        float my_rbf = rbf_lane(dist, j & 7);
        float xr[C];
#pragma unroll
        for (int c = 0; c < C; ++c) xr[c] = x[(size_t)col * C + c];
        float h = b1j;
#pragma unroll
        for (int r = 0; r < R; ++r) {
            float s = 0.f;
#pragma unroll
            for (int c = 0; c < C; ++c)
                s = fmaf(xr[c], Ms[r * C * C + c * C + j], s);
            h = fmaf(__shfl(my_rbf, r, 32), s, h);
        }
        float sh = h / (1.f + __expf(-h));
        float v = b2j;
#pragma unroll
        for (int i = 0; i < C; ++i)
            v = fmaf(__shfl(sh, i, 32), W2s[i * C + j], v);
        atomicAdd(&out[(size_t)row * C + j], v);
    }
}

__global__ void k_add_x(const float* __restrict__ x, float* __restrict__ out, int total) {
    int i = blockIdx.x * blockDim.x + threadIdx.x;
    int stride = gridDim.x * blockDim.x;
    for (; i < total; i += stride) out[i] += x[i];
}

extern "C" void kernel_launch(void* const* d_in, const int* in_sizes, int n_in,
                              void* d_out, int out_size, void* d_ws, size_t ws_size,
                              hipStream_t stream) {
    const float* x   = (const float*)d_in[0];
    const float* pos = (const float*)d_in[1];
    const int*   ei  = (const int*)d_in[2];
    const float* Wtp = (const float*)d_in[3];
    const float* W1  = (const float*)d_in[4];
    const float* b1  = (const float*)d_in[5];
    const float* W2  = (const float*)d_in[6];
    const float* b2  = (const float*)d_in[7];
    int N = in_sizes[0] / C;
    int E = in_sizes[2] / 2;

    char* ws = (char*)d_ws;
    size_t mBytes   = (size_t)R * C * C * sizeof(float);              // 32 KB
    size_t zBytes   = (size_t)N * R * C * sizeof(__hip_bfloat16);     // 25.6 MB
    size_t cntB     = (size_t)N * sizeof(int);                        // 200 KB
    size_t ovfcB    = 64;
    size_t ovfB     = (size_t)OVF_CAP * 16;                           // 1 MB
    size_t rbfsB    = (size_t)E * 16;                                 // 12.8 MB
    size_t ellB     = (size_t)N * K_ELL * 8;                          // 12.8 MB
    size_t aggBytes = (size_t)N * (C + 1) * sizeof(float);            // tier B
    size_t tierANeed = mBytes + zBytes + cntB + ovfcB + ovfB + rbfsB + ellB;
    bool tierA = ws_size >= tierANeed;
    bool tierB = !tierA && ws_size >= mBytes + aggBytes;

    if (tierA) {
        size_t off = 0;
        float*          M      = (float*)(ws + off); off += mBytes;
        __hip_bfloat16* z      = (__hip_bfloat16*)(ws + off); off += zBytes;
        int*            cnt    = (int*)(ws + off); off += cntB;
        int*            ovfcnt = (int*)(ws + off); off += ovfcB;
        uint4*          ovf    = (uint4*)(ws + off); off += ovfB;
        uint4*          rbfs   = (uint4*)(ws + off); off += rbfsB;
        uint2*          ell    = (uint2*)(ws + off);

        // zero cnt + ovfcnt in one memset (adjacent)
        hipMemsetAsync(cnt, 0, cntB + ovfcB, stream);
        k_prepM<<<(R * C * C + 255) / 256, 256, 0, stream>>>(Wtp, W1, M);
        int ZB = (N + NPB - 1) / NPB;
        int SB = (E + 255) / 256;
        k_fused<<<ZB + SB, 256, 0, stream>>>(x, M, z, ei, pos, cnt, ovfcnt, ovf,
                                             rbfs, ell, N, E, ZB);
        int blocks = (int)(((size_t)N * 32 + 255) / 256);
        k_edge_ell<<<blocks, 256, 0, stream>>>(cnt, ell, rbfs, z, x, b1, W2, b2,
                                               (float*)d_out, N);
        k_overflow<<<16, 256, 0, stream>>>(ovfcnt, ovf, rbfs, z, b1, W2,
                                           (float*)d_out, N);
    } else if (tierB) {
        float* M   = (float*)ws;
        float* agg = (float*)(ws + mBytes);
        float* deg = agg + (size_t)N * C;
        hipMemsetAsync(agg, 0, aggBytes, stream);
        k_prepM<<<(R * C * C + 255) / 256, 256, 0, stream>>>(Wtp, W1, M);
        k_edge_direct<<<2048, 256, 0, stream>>>(ei, pos, x, M, b1, agg, deg, E, N);
        k_final<<<1024, 256, 0, stream>>>(x, agg, deg, W2, b2, (float*)d_out, N);
    } else {
        hipMemsetAsync(d_out, 0, (size_t)N * C * sizeof(float), stream);
        k_edge_full<<<1024, 256, 0, stream>>>(ei, pos, x, Wtp, W1, b1, W2, b2,
                                              (float*)d_out, E, N);
        k_add_x<<<1024, 256, 0, stream>>>(x, (float*)d_out, N * C);
    }
}

// Round 12
// 142.044 us; speedup vs baseline: 1.6673x; 1.0993x over previous
//
#include <hip/hip_runtime.h>
#include <hip/hip_bf16.h>

#define C 32
#define R 8
#define NPB 32        // nodes per block in nodeZ part
#define K_ELL 32      // ELL slots per row
#define OVF_CAP 65536

typedef unsigned int u32;
__device__ __forceinline__ float bflo(u32 u) { return __uint_as_float(u << 16); }
__device__ __forceinline__ float bfhi(u32 u) { return __uint_as_float(u & 0xffff0000u); }
__device__ __forceinline__ u32 f2bf_bits(float f) {
    u32 u = __float_as_uint(f);
    u32 lsb = (u >> 16) & 1u;
    return (u + 0x7fffu + lsb) >> 16;
}

// ---- M[r][c][j] = sum_o W_tp[c][r][o] * W1[r*C+o][j]   (f32, 32 KB) ----
__global__ void k_prepM(const float* __restrict__ Wtp, const float* __restrict__ W1,
                        float* __restrict__ M) {
    int idx = blockIdx.x * 256 + threadIdx.x;
    if (idx >= R * C * C) return;
    int r = idx >> 10;
    int c = (idx >> 5) & 31;
    int j = idx & 31;
    float acc = 0.f;
#pragma unroll
    for (int o = 0; o < C; ++o)
        acc = fmaf(Wtp[c * R * C + r * C + o], W1[(r * C + o) * C + j], acc);
    M[idx] = acc;
}

// ---- fused: blocks [0,ZB): nodeZ   |   blocks [ZB,..): per-edge scatter ----
// nodeZ: z[n][j][r] = sum_c x[n][c]*M[r][c][j] (bf16, r contiguous)
// scatter: ell[row*32+local] = {col:16 | bf16(dist):16}; overflow -> list
__global__ void k_fused(const float* __restrict__ x, const float* __restrict__ M,
                        __hip_bfloat16* __restrict__ z,
                        const int* __restrict__ ei, const float* __restrict__ pos,
                        int* __restrict__ cnt, int* __restrict__ ovfcnt,
                        uint4* __restrict__ ovf,
                        u32* __restrict__ ell, int N, int E, int ZB) {
    __shared__ float xs[NPB * C];
    int t = threadIdx.x;
    if ((int)blockIdx.x < ZB) {
        int n0 = blockIdx.x * NPB;
        for (int i = t * 4; i < NPB * C; i += 256 * 4) {
            size_t gbase = (size_t)n0 * C + i;
            float4 v = make_float4(0.f, 0.f, 0.f, 0.f);
            if (gbase + 3 < (size_t)N * C) v = *(const float4*)(x + gbase);
            *(float4*)(xs + i) = v;
        }
        __syncthreads();
        int r = t & 7, j = t >> 3;
        float m[C];
#pragma unroll
        for (int c = 0; c < C; ++c) m[c] = M[r * C * C + c * C + j];
        int nmax = N - n0; if (nmax > NPB) nmax = NPB;
        for (int nn = 0; nn < nmax; ++nn) {
            const float* xp = xs + nn * C;
            float acc = 0.f;
#pragma unroll
            for (int c = 0; c < C; ++c) acc = fmaf(xp[c], m[c], acc);
            z[(size_t)(n0 + nn) * (R * C) + t] = __float2bfloat16(acc);
        }
    } else {
        int i = (blockIdx.x - ZB) * 256 + t;
        if (i < E) {
            int r = ei[i];
            int c = ei[E + i];
            r = ((unsigned)r < (unsigned)N) ? r : 0;
            c = ((unsigned)c < (unsigned)N) ? c : 0;
            float dx = pos[r * 3 + 0] - pos[c * 3 + 0];
            float dy = pos[r * 3 + 1] - pos[c * 3 + 1];
            float dz = pos[r * 3 + 2] - pos[c * 3 + 2];
            float dist = sqrtf(fmaf(dx, dx, fmaf(dy, dy, dz * dz)) + 1e-12f);
            int local = atomicAdd(&cnt[r], 1);
            if (local < K_ELL) {
                ell[(size_t)r * K_ELL + local] = (u32)c | (f2bf_bits(dist) << 16);
            } else {
                int q = atomicAdd(ovfcnt, 1);
                if (q < OVF_CAP)
                    ovf[q] = make_uint4((u32)r, (u32)c, __float_as_uint(dist), 0u);
            }
        }
    }
}

// z slice r (bf16) from a uint4 of 8 bf16
__device__ __forceinline__ float zsl(uint4 zv, int r) {
    u32 w = (r < 2) ? zv.x : (r < 4) ? zv.y : (r < 6) ? zv.z : zv.w;
    return (r & 1) ? bfhi(w) : bflo(w);
}
__device__ __forceinline__ float silu_f(float h) {
    return h * __builtin_amdgcn_rcpf(1.f + __expf(-h));
}
// rbf at center r (f32): centers linspace(0,5,8), width 5/7, scale 1/sqrt(2pi)
__device__ __forceinline__ float rbf_at(float dist, int r) {
    float t = (dist - 0.71428573f * (float)r) * 1.3999999f;
    return 0.3989423f * __expf(-0.5f * t * t);
}

// ---- per-row ELL edge kernel: 32 lanes = one row; fused W2/b2 epilogue ----
__global__ void k_edge_ell(const int* __restrict__ cnt, const u32* __restrict__ ell,
                           const __hip_bfloat16* __restrict__ z,
                           const float* __restrict__ x, const float* __restrict__ b1,
                           const float* __restrict__ W2, const float* __restrict__ b2,
                           float* __restrict__ out, int N) {
    __shared__ float W2s[C * C];
    for (int i = threadIdx.x; i < C * C; i += blockDim.x) W2s[i] = W2[i];
    __syncthreads();
    int gt = blockIdx.x * blockDim.x + threadIdx.x;
    int j = gt & 31;
    int n = gt >> 5;
    if (n >= N) return;
    int deg = cnt[n];
    int m = deg < K_ELL ? deg : K_ELL;
    u32 packv = 0u;
    if (j < m) packv = ell[(size_t)n * K_ELL + j];
    float b1j = b1[j];
    float acc = 0.f;
    int base = 0;
    for (; base + 4 <= m; base += 4) {
        // lane j serves edge (base + j>>3) at center (j&7): ONE exp per 4 edges
        u32 wmy = __shfl(packv, base + (j >> 3), 32);
        float dmy = __uint_as_float(wmy & 0xffff0000u);
        float my = rbf_at(dmy, j & 7);
        u32 w0 = __shfl(packv, base + 0, 32);
        u32 w1 = __shfl(packv, base + 1, 32);
        u32 w2 = __shfl(packv, base + 2, 32);
        u32 w3 = __shfl(packv, base + 3, 32);
        uint4 z0 = ((const uint4*)(z + (size_t)(w0 & 0xffffu) * (R * C)))[j];
        uint4 z1 = ((const uint4*)(z + (size_t)(w1 & 0xffffu) * (R * C)))[j];
        uint4 z2 = ((const uint4*)(z + (size_t)(w2 & 0xffffu) * (R * C)))[j];
        uint4 z3 = ((const uint4*)(z + (size_t)(w3 & 0xffffu) * (R * C)))[j];
        float h0 = b1j, h1 = b1j, h2 = b1j, h3 = b1j;
#pragma unroll
        for (int r = 0; r < R; ++r) {
            h0 = fmaf(__shfl(my, 0 * 8 + r, 32), zsl(z0, r), h0);
            h1 = fmaf(__shfl(my, 1 * 8 + r, 32), zsl(z1, r), h1);
            h2 = fmaf(__shfl(my, 2 * 8 + r, 32), zsl(z2, r), h2);
            h3 = fmaf(__shfl(my, 3 * 8 + r, 32), zsl(z3, r), h3);
        }
        acc += silu_f(h0) + silu_f(h1) + silu_f(h2) + silu_f(h3);
    }
    for (; base < m; ++base) {
        u32 w0 = __shfl(packv, base, 32);
        float d0 = __uint_as_float(w0 & 0xffff0000u);
        float my = rbf_at(d0, j & 7);
        uint4 z0 = ((const uint4*)(z + (size_t)(w0 & 0xffffu) * (R * C)))[j];
        float h0 = b1j;
#pragma unroll
        for (int r = 0; r < R; ++r)
            h0 = fmaf(__shfl(my, r, 32), zsl(z0, r), h0);
        acc += silu_f(h0);
    }
    // out[n][j] = x[n][j] + sum_i acc_i*W2[i][j] + deg*b2[j]   (deg = TRUE degree)
    float v = fmaf((float)deg, b2[j], x[(size_t)n * C + j]);
#pragma unroll
    for (int i = 0; i < C; ++i)
        v = fmaf(__shfl(acc, i, 32), W2s[i * C + j], v);
    out[(size_t)n * C + j] = v;
}

// ---- overflow fix-up: add W2-weighted silu of overflow edges (b2 already counted) ----
__global__ void k_overflow(const int* __restrict__ ovfcnt, const uint4* __restrict__ ovf,
                           const __hip_bfloat16* __restrict__ z,
                           const float* __restrict__ b1, const float* __restrict__ W2,
                           float* __restrict__ out, int N) {
    int novf = ovfcnt[0];
    if (novf > OVF_CAP) novf = OVF_CAP;
    int gt = blockIdx.x * blockDim.x + threadIdx.x;
    int j = gt & 31;
    int g = gt >> 5;
    int ngroups = (gridDim.x * blockDim.x) >> 5;
    for (int q = g; q < novf; q += ngroups) {
        uint4 rec = ovf[q];
        u32 row = rec.x, col = rec.y;
        float dist = __uint_as_float(rec.z);
        float my = rbf_at(dist, j & 7);
        uint4 zv = ((const uint4*)(z + (size_t)col * (R * C)))[j];
        float h = b1[j];
#pragma unroll
        for (int r = 0; r < R; ++r)
            h = fmaf(__shfl(my, r, 32), zsl(zv, r), h);
        float sh = silu_f(h);
        float v = 0.f;
#pragma unroll
        for (int i = 0; i < C; ++i)
            v = fmaf(__shfl(sh, i, 32), W2[i * C + j], v);
        atomicAdd(&out[(size_t)row * C + j], v);
    }
}

// rbf for fallback tiers
__device__ __forceinline__ float rbf_lane(float dist, int r) {
    float t = (dist - 0.71428573f * (float)r) * 1.3999999f;
    return 0.3989423f * __expf(-0.5f * t * t);
}

// ---- Tier B kernels (proven fallback) ----
__global__ void k_edge_direct(const int* __restrict__ ei, const float* __restrict__ pos,
                              const float* __restrict__ x, const float* __restrict__ M,
                              const float* __restrict__ b1,
                              float* __restrict__ agg, float* __restrict__ deg,
                              int E, int N) {
    __shared__ float Ms[R * C * C];
    for (int i = threadIdx.x; i < R * C * C; i += blockDim.x) Ms[i] = M[i];
    __syncthreads();
    int gt = blockIdx.x * blockDim.x + threadIdx.x;
    int j = gt & 31;
    int g = gt >> 5;
    int ngroups = (gridDim.x * blockDim.x) >> 5;
    float b1j = b1[j];
    for (int e = g; e < E; e += ngroups) {
        int row = ei[e];
        int col = ei[E + e];
        row = ((unsigned)row < (unsigned)N) ? row : 0;
        col = ((unsigned)col < (unsigned)N) ? col : 0;
        float dx = pos[row * 3 + 0] - pos[col * 3 + 0];
        float dy = pos[row * 3 + 1] - pos[col * 3 + 1];
        float dz = pos[row * 3 + 2] - pos[col * 3 + 2];
        float dist = sqrtf(fmaf(dx, dx, fmaf(dy, dy, dz * dz)) + 1e-12f);
        float my_rbf = rbf_lane(dist, j & 7);
        float xr[C];
#pragma unroll
        for (int c = 0; c < C; ++c) xr[c] = x[(size_t)col * C + c];
        float h = b1j;
#pragma unroll
        for (int r = 0; r < R; ++r) {
            float s = 0.f;
#pragma unroll
            for (int c = 0; c < C; ++c)
                s = fmaf(xr[c], Ms[r * C * C + c * C + j], s);
            h = fmaf(__shfl(my_rbf, r, 32), s, h);
        }
        float sh = h / (1.f + __expf(-h));
        atomicAdd(&agg[(size_t)row * C + j], sh);
        if (j == 0) atomicAdd(&deg[row], 1.f);
    }
}

__global__ void k_final(const float* __restrict__ x, const float* __restrict__ agg,
                        const float* __restrict__ deg, const float* __restrict__ W2,
                        const float* __restrict__ b2, float* __restrict__ out,
                        int N) {
    int t = threadIdx.x;
    int j = t & 31;
    float w2[C];
#pragma unroll
    for (int i = 0; i < C; ++i) w2[i] = W2[i * C + j];
    float b2j = b2[j];
    int g = (blockIdx.x * blockDim.x + t) >> 5;
    int ngroups = (gridDim.x * blockDim.x) >> 5;
    for (int n = g; n < N; n += ngroups) {
        const float* ap = agg + (size_t)n * C;
        float acc = 0.f;
#pragma unroll
        for (int i = 0; i < C; ++i) acc = fmaf(ap[i], w2[i], acc);
        out[(size_t)n * C + j] = x[(size_t)n * C + j] + acc + deg[n] * b2j;
    }
}

// ---- Tier C (no usable ws) ----
__global__ void k_edge_full(const int* __restrict__ ei, const float* __restrict__ pos,
                            const float* __restrict__ x,
                            const float* __restrict__ Wtp, const float* __restrict__ W1,
                            const float* __restrict__ b1,
                            const float* __restrict__ W2, const float* __restrict__ b2,
                            float* __restrict__ out, int E, int N) {
    __shared__ float Ms[R * C * C];
    __shared__ float W2s[C * C];
    for (int idx = threadIdx.x; idx < R * C * C; idx += blockDim.x) {
        int r = idx >> 10, c = (idx >> 5) & 31, jj = idx & 31;
        float acc = 0.f;
#pragma unroll
        for (int o = 0; o < C; ++o)
            acc = fmaf(Wtp[c * R * C + r * C + o], W1[(r * C + o) * C + jj], acc);
        Ms[idx] = acc;
    }
    for (int idx = threadIdx.x; idx < C * C; idx += blockDim.x) W2s[idx] = W2[idx];
    __syncthreads();
    int gt = blockIdx.x * blockDim.x + threadIdx.x;
    int j = gt & 31;
    int g = gt >> 5;
    int ngroups = (gridDim.x * blockDim.x) >> 5;
    float b1j = b1[j];
    float b2j = b2[j];
    for (int e = g; e < E; e += ngroups) {
        int row = ei[e];
        int col = ei[E + e];
        row = ((unsigned)row < (unsigned)N) ? row : 0;
        col = ((unsigned)col < (unsigned)N) ? col : 0;
        float dx = pos[row * 3 + 0] - pos[col * 3 + 0];
        float dy = pos[row * 3 + 1] - pos[col * 3 + 1];
        float dz = pos[row * 3 + 2] - pos[col * 3 + 2];
        float dist = sqrtf(fmaf(dx, dx, fmaf(dy, dy, dz * dz)) + 1e-12f);
        float my_rbf = rbf_lane(dist, j & 7);
        float xr[C];
#pragma unroll
        for (int c = 0; c < C; ++c) xr[c] = x[(size_t)col * C + c];
        float h = b1j;
#pragma unroll
        for (int r = 0; r < R; ++r) {
            float s = 0.f;
#pragma unroll
            for (int c = 0; c < C; ++c)
                s = fmaf(xr[c], Ms[r * C * C + c * C + j], s);
            h = fmaf(__shfl(my_rbf, r, 32), s, h);
        }
        float sh = h / (1.f + __expf(-h));
        float v = b2j;
#pragma unroll
        for (int i = 0; i < C; ++i)
            v = fmaf(__shfl(sh, i, 32), W2s[i * C + j], v);
        atomicAdd(&out[(size_t)row * C + j], v);
    }
}

__global__ void k_add_x(const float* __restrict__ x, float* __restrict__ out, int total) {
    int i = blockIdx.x * blockDim.x + threadIdx.x;
    int stride = gridDim.x * blockDim.x;
    for (; i < total; i += stride) out[i] += x[i];
}

extern "C" void kernel_launch(void* const* d_in, const int* in_sizes, int n_in,
                              void* d_out, int out_size, void* d_ws, size_t ws_size,
                              hipStream_t stream) {
    const float* x   = (const float*)d_in[0];
    const float* pos = (const float*)d_in[1];
    const int*   ei  = (const int*)d_in[2];
    const float* Wtp = (const float*)d_in[3];
    const float* W1  = (const float*)d_in[4];
    const float* b1  = (const float*)d_in[5];
    const float* W2  = (const float*)d_in[6];
    const float* b2  = (const float*)d_in[7];
    int N = in_sizes[0] / C;
    int E = in_sizes[2] / 2;

    char* ws = (char*)d_ws;
    size_t mBytes   = (size_t)R * C * C * sizeof(float);              // 32 KB
    size_t zBytes   = (size_t)N * R * C * sizeof(__hip_bfloat16);     // 25.6 MB
    size_t cntB     = (size_t)N * sizeof(int);                        // 200 KB
    size_t ovfcB    = 64;
    size_t ovfB     = (size_t)OVF_CAP * 16;                           // 1 MB
    size_t ellB     = (size_t)N * K_ELL * sizeof(u32);                // 6.4 MB
    size_t aggBytes = (size_t)N * (C + 1) * sizeof(float);            // tier B
    size_t tierANeed = mBytes + zBytes + cntB + ovfcB + ovfB + ellB;
    bool tierA = (ws_size >= tierANeed) && (N <= 65535);
    bool tierB = !tierA && ws_size >= mBytes + aggBytes;

    if (tierA) {
        size_t off = 0;
        float*          M      = (float*)(ws + off); off += mBytes;
        __hip_bfloat16* z      = (__hip_bfloat16*)(ws + off); off += zBytes;
        int*            cnt    = (int*)(ws + off); off += cntB;
        int*            ovfcnt = (int*)(ws + off); off += ovfcB;
        uint4*          ovf    = (uint4*)(ws + off); off += ovfB;
        u32*            ell    = (u32*)(ws + off);

        hipMemsetAsync(cnt, 0, cntB + ovfcB, stream);  // cnt + ovfcnt adjacent
        k_prepM<<<(R * C * C + 255) / 256, 256, 0, stream>>>(Wtp, W1, M);
        int ZB = (N + NPB - 1) / NPB;
        int SB = (E + 255) / 256;
        k_fused<<<ZB + SB, 256, 0, stream>>>(x, M, z, ei, pos, cnt, ovfcnt, ovf,
                                             ell, N, E, ZB);
        int blocks = (int)(((size_t)N * 32 + 255) / 256);
        k_edge_ell<<<blocks, 256, 0, stream>>>(cnt, ell, z, x, b1, W2, b2,
                                               (float*)d_out, N);
        k_overflow<<<16, 256, 0, stream>>>(ovfcnt, ovf, z, b1, W2,
                                           (float*)d_out, N);
    } else if (tierB) {
        float* M   = (float*)ws;
        float* agg = (float*)(ws + mBytes);
        float* deg = agg + (size_t)N * C;
        hipMemsetAsync(agg, 0, aggBytes, stream);
        k_prepM<<<(R * C * C + 255) / 256, 256, 0, stream>>>(Wtp, W1, M);
        k_edge_direct<<<2048, 256, 0, stream>>>(ei, pos, x, M, b1, agg, deg, E, N);
        k_final<<<1024, 256, 0, stream>>>(x, agg, deg, W2, b2, (float*)d_out, N);
    } else {
        hipMemsetAsync(d_out, 0, (size_t)N * C * sizeof(float), stream);
        k_edge_full<<<1024, 256, 0, stream>>>(ei, pos, x, Wtp, W1, b1, W2, b2,
                                              (float*)d_out, E, N);
        k_add_x<<<1024, 256, 0, stream>>>(x, (float*)d_out, N * C);
    }
}

// Round 13
// 128.740 us; speedup vs baseline: 1.8396x; 1.1033x over previous
//
#include <hip/hip_runtime.h>
#include <hip/hip_bf16.h>

#define C 32
#define R 8
#define NPB 32        // nodes per block in nodeZ part
#define K_ELL 32      // ELL slots per row
#define OVF_CAP 65536

typedef unsigned int u32;
__device__ __forceinline__ float bflo(u32 u) { return __uint_as_float(u << 16); }
__device__ __forceinline__ float bfhi(u32 u) { return __uint_as_float(u & 0xffff0000u); }
__device__ __forceinline__ u32 f2bf_bits(float f) {
    u32 u = __float_as_uint(f);
    u32 lsb = (u >> 16) & 1u;
    return (u + 0x7fffu + lsb) >> 16;
}

// ---- M[r][c][j] = sum_o W_tp[c][r][o] * W1[r*C+o][j]   (f32, 32 KB) ----
__global__ void k_prepM(const float* __restrict__ Wtp, const float* __restrict__ W1,
                        float* __restrict__ M) {
    int idx = blockIdx.x * 256 + threadIdx.x;
    if (idx >= R * C * C) return;
    int r = idx >> 10;
    int c = (idx >> 5) & 31;
    int j = idx & 31;
    float acc = 0.f;
#pragma unroll
    for (int o = 0; o < C; ++o)
        acc = fmaf(Wtp[c * R * C + r * C + o], W1[(r * C + o) * C + j], acc);
    M[idx] = acc;
}

// ---- fused: blocks [0,ZB): nodeZ   |   blocks [ZB,..): per-edge scatter ----
__global__ void k_fused(const float* __restrict__ x, const float* __restrict__ M,
                        __hip_bfloat16* __restrict__ z,
                        const int* __restrict__ ei, const float* __restrict__ pos,
                        int* __restrict__ cnt, int* __restrict__ ovfcnt,
                        uint4* __restrict__ ovf,
                        u32* __restrict__ ell, int N, int E, int ZB) {
    __shared__ float xs[NPB * C];
    int t = threadIdx.x;
    if ((int)blockIdx.x < ZB) {
        int n0 = blockIdx.x * NPB;
        for (int i = t * 4; i < NPB * C; i += 256 * 4) {
            size_t gbase = (size_t)n0 * C + i;
            float4 v = make_float4(0.f, 0.f, 0.f, 0.f);
            if (gbase + 3 < (size_t)N * C) v = *(const float4*)(x + gbase);
            *(float4*)(xs + i) = v;
        }
        __syncthreads();
        int r = t & 7, j = t >> 3;
        float m[C];
#pragma unroll
        for (int c = 0; c < C; ++c) m[c] = M[r * C * C + c * C + j];
        int nmax = N - n0; if (nmax > NPB) nmax = NPB;
        for (int nn = 0; nn < nmax; ++nn) {
            const float* xp = xs + nn * C;
            float acc = 0.f;
#pragma unroll
            for (int c = 0; c < C; ++c) acc = fmaf(xp[c], m[c], acc);
            z[(size_t)(n0 + nn) * (R * C) + t] = __float2bfloat16(acc);
        }
    } else {
        int i = (blockIdx.x - ZB) * 256 + t;
        if (i < E) {
            int r = ei[i];
            int c = ei[E + i];
            r = ((unsigned)r < (unsigned)N) ? r : 0;
            c = ((unsigned)c < (unsigned)N) ? c : 0;
            float dx = pos[r * 3 + 0] - pos[c * 3 + 0];
            float dy = pos[r * 3 + 1] - pos[c * 3 + 1];
            float dz = pos[r * 3 + 2] - pos[c * 3 + 2];
            float dist = sqrtf(fmaf(dx, dx, fmaf(dy, dy, dz * dz)) + 1e-12f);
            int local = atomicAdd(&cnt[r], 1);
            if (local < K_ELL) {
                ell[(size_t)r * K_ELL + local] = (u32)c | (f2bf_bits(dist) << 16);
            } else {
                int q = atomicAdd(ovfcnt, 1);
                if (q < OVF_CAP)
                    ovf[q] = make_uint4((u32)r, (u32)c, __float_as_uint(dist), 0u);
            }
        }
    }
}

__device__ __forceinline__ float silu_f(float h) {
    return h * __builtin_amdgcn_rcpf(1.f + __expf(-h));
}

// per-lane full-rbf dot: h = b1j + sum_r rbf(d,r)*z_r  — 2 exps, no shuffles.
// rbf[r] = s*exp(-0.5(u-r)^2), u=d/w, w=5/7:  f_{r+1}=f_r*m_r, m_0=exp(u-1/2),
// m_{r+1}=m_r*e^-1.
__device__ __forceinline__ float rbf_dot(float d, uint4 zv, float b1j) {
    const float Einv = 0.36787944f;   // e^-1
    float u = 1.3999999f * d;
    float f = 0.3989423f * __expf(-0.5f * u * u);
    float t = __expf(u - 0.5f);
    float h = fmaf(f, bflo(zv.x), b1j);
    f *= t;            h = fmaf(f, bfhi(zv.x), h);
    t *= Einv; f *= t; h = fmaf(f, bflo(zv.y), h);
    t *= Einv; f *= t; h = fmaf(f, bfhi(zv.y), h);
    t *= Einv; f *= t; h = fmaf(f, bflo(zv.z), h);
    t *= Einv; f *= t; h = fmaf(f, bfhi(zv.z), h);
    t *= Einv; f *= t; h = fmaf(f, bflo(zv.w), h);
    t *= Einv; f *= t; h = fmaf(f, bfhi(zv.w), h);
    return h;
}

// ---- per-row ELL edge kernel: 32 lanes = one row; fused W2/b2 epilogue ----
__global__ void k_edge_ell(const int* __restrict__ cnt, const u32* __restrict__ ell,
                           const __hip_bfloat16* __restrict__ z,
                           const float* __restrict__ x, const float* __restrict__ b1,
                           const float* __restrict__ W2, const float* __restrict__ b2,
                           float* __restrict__ out, int N) {
    __shared__ float W2s[C * C];
    for (int i = threadIdx.x; i < C * C; i += blockDim.x) W2s[i] = W2[i];
    __syncthreads();
    int gt = blockIdx.x * blockDim.x + threadIdx.x;
    int j = gt & 31;
    int n = gt >> 5;
    if (n >= N) return;
    int deg = cnt[n];
    int m = deg < K_ELL ? deg : K_ELL;
    u32 packv = 0u;
    if (j < m) packv = ell[(size_t)n * K_ELL + j];
    float b1j = b1[j];
    float acc = 0.f;
    int base = 0;
    for (; base + 4 <= m; base += 4) {
        u32 w0 = __shfl(packv, base + 0, 32);
        u32 w1 = __shfl(packv, base + 1, 32);
        u32 w2 = __shfl(packv, base + 2, 32);
        u32 w3 = __shfl(packv, base + 3, 32);
        uint4 z0 = ((const uint4*)(z + (size_t)(w0 & 0xffffu) * (R * C)))[j];
        uint4 z1 = ((const uint4*)(z + (size_t)(w1 & 0xffffu) * (R * C)))[j];
        uint4 z2 = ((const uint4*)(z + (size_t)(w2 & 0xffffu) * (R * C)))[j];
        uint4 z3 = ((const uint4*)(z + (size_t)(w3 & 0xffffu) * (R * C)))[j];
        float h0 = rbf_dot(__uint_as_float(w0 & 0xffff0000u), z0, b1j);
        float h1 = rbf_dot(__uint_as_float(w1 & 0xffff0000u), z1, b1j);
        float h2 = rbf_dot(__uint_as_float(w2 & 0xffff0000u), z2, b1j);
        float h3 = rbf_dot(__uint_as_float(w3 & 0xffff0000u), z3, b1j);
        acc += silu_f(h0) + silu_f(h1) + silu_f(h2) + silu_f(h3);
    }
    for (; base < m; ++base) {
        u32 w0 = __shfl(packv, base, 32);
        uint4 z0 = ((const uint4*)(z + (size_t)(w0 & 0xffffu) * (R * C)))[j];
        acc += silu_f(rbf_dot(__uint_as_float(w0 & 0xffff0000u), z0, b1j));
    }
    // out[n][j] = x[n][j] + sum_i acc_i*W2[i][j] + deg*b2[j]   (deg = TRUE degree)
    float v = fmaf((float)deg, b2[j], x[(size_t)n * C + j]);
#pragma unroll
    for (int i = 0; i < C; ++i)
        v = fmaf(__shfl(acc, i, 32), W2s[i * C + j], v);
    out[(size_t)n * C + j] = v;
}

// ---- overflow fix-up: add W2-weighted silu of overflow edges (b2 already counted) ----
__global__ void k_overflow(const int* __restrict__ ovfcnt, const uint4* __restrict__ ovf,
                           const __hip_bfloat16* __restrict__ z,
                           const float* __restrict__ b1, const float* __restrict__ W2,
                           float* __restrict__ out, int N) {
    int novf = ovfcnt[0];
    if (novf > OVF_CAP) novf = OVF_CAP;
    int gt = blockIdx.x * blockDim.x + threadIdx.x;
    int j = gt & 31;
    int g = gt >> 5;
    int ngroups = (gridDim.x * blockDim.x) >> 5;
    for (int q = g; q < novf; q += ngroups) {
        uint4 rec = ovf[q];
        u32 row = rec.x, col = rec.y;
        float dist = __uint_as_float(rec.z);
        uint4 zv = ((const uint4*)(z + (size_t)col * (R * C)))[j];
        float sh = silu_f(rbf_dot(dist, zv, b1[j]));
        float v = 0.f;
#pragma unroll
        for (int i = 0; i < C; ++i)
            v = fmaf(__shfl(sh, i, 32), W2[i * C + j], v);
        atomicAdd(&out[(size_t)row * C + j], v);
    }
}

// rbf for fallback tiers
__device__ __forceinline__ float rbf_lane(float dist, int r) {
    float t = (dist - 0.71428573f * (float)r) * 1.3999999f;
    return 0.3989423f * __expf(-0.5f * t * t);
}

// ---- Tier B kernels (proven fallback) ----
__global__ void k_edge_direct(const int* __restrict__ ei, const float* __restrict__ pos,
                              const float* __restrict__ x, const float* __restrict__ M,
                              const float* __restrict__ b1,
                              float* __restrict__ agg, float* __restrict__ deg,
                              int E, int N) {
    __shared__ float Ms[R * C * C];
    for (int i = threadIdx.x; i < R * C * C; i += blockDim.x) Ms[i] = M[i];
    __syncthreads();
    int gt = blockIdx.x * blockDim.x + threadIdx.x;
    int j = gt & 31;
    int g = gt >> 5;
    int ngroups = (gridDim.x * blockDim.x) >> 5;
    float b1j = b1[j];
    for (int e = g; e < E; e += ngroups) {
        int row = ei[e];
        int col = ei[E + e];
        row = ((unsigned)row < (unsigned)N) ? row : 0;
        col = ((unsigned)col < (unsigned)N) ? col : 0;
        float dx = pos[row * 3 + 0] - pos[col * 3 + 0];
        float dy = pos[row * 3 + 1] - pos[col * 3 + 1];
        float dz = pos[row * 3 + 2] - pos[col * 3 + 2];
        float dist = sqrtf(fmaf(dx, dx, fmaf(dy, dy, dz * dz)) + 1e-12f);
        float my_rbf = rbf_lane(dist, j & 7);
        float xr[C];
#pragma unroll
        for (int c = 0; c < C; ++c) xr[c] = x[(size_t)col * C + c];
        float h = b1j;
#pragma unroll
        for (int r = 0; r < R; ++r) {
            float s = 0.f;
#pragma unroll
            for (int c = 0; c < C; ++c)
                s = fmaf(xr[c], Ms[r * C * C + c * C + j], s);
            h = fmaf(__shfl(my_rbf, r, 32), s, h);
        }
        float sh = h / (1.f + __expf(-h));
        atomicAdd(&agg[(size_t)row * C + j], sh);
        if (j == 0) atomicAdd(&deg[row], 1.f);
    }
}

__global__ void k_final(const float* __restrict__ x, const float* __restrict__ agg,
                        const float* __restrict__ deg, const float* __restrict__ W2,
                        const float* __restrict__ b2, float* __restrict__ out,
                        int N) {
    int t = threadIdx.x;
    int j = t & 31;
    float w2[C];
#pragma unroll
    for (int i = 0; i < C; ++i) w2[i] = W2[i * C + j];
    float b2j = b2[j];
    int g = (blockIdx.x * blockDim.x + t) >> 5;
    int ngroups = (gridDim.x * blockDim.x) >> 5;
    for (int n = g; n < N; n += ngroups) {
        const float* ap = agg + (size_t)n * C;
        float acc = 0.f;
#pragma unroll
        for (int i = 0; i < C; ++i) acc = fmaf(ap[i], w2[i], acc);
        out[(size_t)n * C + j] = x[(size_t)n * C + j] + acc + deg[n] * b2j;
    }
}

// ---- Tier C (no usable ws) ----
__global__ void k_edge_full(const int* __restrict__ ei, const float* __restrict__ pos,
                            const float* __restrict__ x,
                            const float* __restrict__ Wtp, const float* __restrict__ W1,
                            const float* __restrict__ b1,
                            const float* __restrict__ W2, const float* __restrict__ b2,
                            float* __restrict__ out, int E, int N) {
    __shared__ float Ms[R * C * C];
    __shared__ float W2s[C * C];
    for (int idx = threadIdx.x; idx < R * C * C; idx += blockDim.x) {
        int r = idx >> 10, c = (idx >> 5) & 31, jj = idx & 31;
        float acc = 0.f;
#pragma unroll
        for (int o = 0; o < C; ++o)
            acc = fmaf(Wtp[c * R * C + r * C + o], W1[(r * C + o) * C + jj], acc);
        Ms[idx] = acc;
    }
    for (int idx = threadIdx.x; idx < C * C; idx += blockDim.x) W2s[idx] = W2[idx];
    __syncthreads();
    int gt = blockIdx.x * blockDim.x + threadIdx.x;
    int j = gt & 31;
    int g = gt >> 5;
    int ngroups = (gridDim.x * blockDim.x) >> 5;
    float b1j = b1[j];
    float b2j = b2[j];
    for (int e = g; e < E; e += ngroups) {
        int row = ei[e];
        int col = ei[E + e];
        row = ((unsigned)row < (unsigned)N) ? row : 0;
        col = ((unsigned)col < (unsigned)N) ? col : 0;
        float dx = pos[row * 3 + 0] - pos[col * 3 + 0];
        float dy = pos[row * 3 + 1] - pos[col * 3 + 1];
        float dz = pos[row * 3 + 2] - pos[col * 3 + 2];
        float dist = sqrtf(fmaf(dx, dx, fmaf(dy, dy, dz * dz)) + 1e-12f);
        float my_rbf = rbf_lane(dist, j & 7);
        float xr[C];
#pragma unroll
        for (int c = 0; c < C; ++c) xr[c] = x[(size_t)col * C + c];
        float h = b1j;
#pragma unroll
        for (int r = 0; r < R; ++r) {
            float s = 0.f;
#pragma unroll
            for (int c = 0; c < C; ++c)
                s = fmaf(xr[c], Ms[r * C * C + c * C + j], s);
            h = fmaf(__shfl(my_rbf, r, 32), s, h);
        }
        float sh = h / (1.f + __expf(-h));
        float v = b2j;
#pragma unroll
        for (int i = 0; i < C; ++i)
            v = fmaf(__shfl(sh, i, 32), W2s[i * C + j], v);
        atomicAdd(&out[(size_t)row * C + j], v);
    }
}

__global__ void k_add_x(const float* __restrict__ x, float* __restrict__ out, int total) {
    int i = blockIdx.x * blockDim.x + threadIdx.x;
    int stride = gridDim.x * blockDim.x;
    for (; i < total; i += stride) out[i] += x[i];
}

extern "C" void kernel_launch(void* const* d_in, const int* in_sizes, int n_in,
                              void* d_out, int out_size, void* d_ws, size_t ws_size,
                              hipStream_t stream) {
    const float* x   = (const float*)d_in[0];
    const float* pos = (const float*)d_in[1];
    const int*   ei  = (const int*)d_in[2];
    const float* Wtp = (const float*)d_in[3];
    const float* W1  = (const float*)d_in[4];
    const float* b1  = (const float*)d_in[5];
    const float* W2  = (const float*)d_in[6];
    const float* b2  = (const float*)d_in[7];
    int N = in_sizes[0] / C;
    int E = in_sizes[2] / 2;

    char* ws = (char*)d_ws;
    size_t mBytes   = (size_t)R * C * C * sizeof(float);              // 32 KB
    size_t zBytes   = (size_t)N * R * C * sizeof(__hip_bfloat16);     // 25.6 MB
    size_t cntB     = (size_t)N * sizeof(int);                        // 200 KB
    size_t ovfcB    = 64;
    size_t ovfB     = (size_t)OVF_CAP * 16;                           // 1 MB
    size_t ellB     = (size_t)N * K_ELL * sizeof(u32);                // 6.4 MB
    size_t aggBytes = (size_t)N * (C + 1) * sizeof(float);            // tier B
    size_t tierANeed = mBytes + zBytes + cntB + ovfcB + ovfB + ellB;
    bool tierA = (ws_size >= tierANeed) && (N <= 65535);
    bool tierB = !tierA && ws_size >= mBytes + aggBytes;

    if (tierA) {
        size_t off = 0;
        float*          M      = (float*)(ws + off); off += mBytes;
        __hip_bfloat16* z      = (__hip_bfloat16*)(ws + off); off += zBytes;
        int*            cnt    = (int*)(ws + off); off += cntB;
        int*            ovfcnt = (int*)(ws + off); off += ovfcB;
        uint4*          ovf    = (uint4*)(ws + off); off += ovfB;
        u32*            ell    = (u32*)(ws + off);

        hipMemsetAsync(cnt, 0, cntB + ovfcB, stream);  // cnt + ovfcnt adjacent
        k_prepM<<<(R * C * C + 255) / 256, 256, 0, stream>>>(Wtp, W1, M);
        int ZB = (N + NPB - 1) / NPB;
        int SB = (E + 255) / 256;
        k_fused<<<ZB + SB, 256, 0, stream>>>(x, M, z, ei, pos, cnt, ovfcnt, ovf,
                                             ell, N, E, ZB);
        int blocks = (int)(((size_t)N * 32 + 255) / 256);
        k_edge_ell<<<blocks, 256, 0, stream>>>(cnt, ell, z, x, b1, W2, b2,
                                               (float*)d_out, N);
        k_overflow<<<16, 256, 0, stream>>>(ovfcnt, ovf, z, b1, W2,
                                           (float*)d_out, N);
    } else if (tierB) {
        float* M   = (float*)ws;
        float* agg = (float*)(ws + mBytes);
        float* deg = agg + (size_t)N * C;
        hipMemsetAsync(agg, 0, aggBytes, stream);
        k_prepM<<<(R * C * C + 255) / 256, 256, 0, stream>>>(Wtp, W1, M);
        k_edge_direct<<<2048, 256, 0, stream>>>(ei, pos, x, M, b1, agg, deg, E, N);
        k_final<<<1024, 256, 0, stream>>>(x, agg, deg, W2, b2, (float*)d_out, N);
    } else {
        hipMemsetAsync(d_out, 0, (size_t)N * C * sizeof(float), stream);
        k_edge_full<<<1024, 256, 0, stream>>>(ei, pos, x, Wtp, W1, b1, W2, b2,
                                              (float*)d_out, E, N);
        k_add_x<<<1024, 256, 0, stream>>>(x, (float*)d_out, N * C);
    }
}